// Round 9
// baseline (1254.877 us; speedup 1.0000x reference)
//
#include <hip/hip_runtime.h>

// SAModule (PointNet++): FPS -> kNN(32) -> [x||rel] MLP(67->128->128->256) -> max over K.
// B=16, N=4096, C=64, M=1024, K=32.
// R8: FPS processes TWO independent clouds per 256-thread block (8 FPS blocks).
// The two clouds' dep chains interleave in-wave, filling latency slots that a
// single cloud leaves idle (R3 showed same-cloud extra waves don't help).
// Workers (fence-free ipub polling, R7) unchanged.

#define B_    16
#define N_    4096
#define M_    1024
#define AST   136
#define NFPSB 8            // FPS blocks, 2 clouds each
#define NWORK 240
#define NITEM (256 * 16)   // items ordered mset-major: it = mset*16 + b

typedef __bf16 bf16x8 __attribute__((ext_vector_type(8)));
typedef __bf16 bf16x4 __attribute__((ext_vector_type(4)));
typedef float  f32x4  __attribute__((ext_vector_type(4)));
typedef float  f32x2  __attribute__((ext_vector_type(2)));

// ---------------------------------------------------------------------------
// Weight prep: transpose + cast to bf16, pad W1 K-dim 67->96 with zeros.
// ---------------------------------------------------------------------------
__global__ __launch_bounds__(256) void prep_weights(
    const float* __restrict__ W1, const float* __restrict__ W2,
    const float* __restrict__ W3,
    __bf16* __restrict__ w1t, __bf16* __restrict__ w2t, __bf16* __restrict__ w3t) {
  const int t = blockIdx.x * 256 + threadIdx.x;   // 0..32767
  if (t < 128 * 96) {
    const int n = t / 96, k = t % 96;
    w1t[t] = (k < 67) ? (__bf16)W1[k * 128 + n] : (__bf16)0.0f;
  }
  if (t < 128 * 128) {
    const int n = t >> 7, k = t & 127;
    w2t[t] = (__bf16)W2[k * 128 + n];
  }
  {
    const int n = t >> 7, k = t & 127;   // t < 256*128 always
    w3t[t] = (__bf16)W3[k * 256 + n];
  }
}

// ---------------------------------------------------------------------------
__device__ __forceinline__ f32x2 pk_sub(f32x2 a, f32x2 b) {
  f32x2 d;
  asm("v_pk_add_f32 %0, %1, %2 neg_lo:[0,1] neg_hi:[0,1]" : "=v"(d) : "v"(a), "v"(b));
  return d;
}
__device__ __forceinline__ f32x2 pk_mul(f32x2 a, f32x2 b) {
  f32x2 d;
  asm("v_pk_mul_f32 %0, %1, %2" : "=v"(d) : "v"(a), "v"(b));
  return d;
}
__device__ __forceinline__ f32x2 pk_add(f32x2 a, f32x2 b) {
  f32x2 d;
  asm("v_pk_add_f32 %0, %1, %2" : "=v"(d) : "v"(a), "v"(b));
  return d;
}

template <int CTRL>
__device__ __forceinline__ unsigned long long dpp_max_u64(unsigned long long k) {
  unsigned lo = (unsigned)__builtin_amdgcn_update_dpp(0, (int)(unsigned)k,         CTRL, 0xF, 0xF, true);
  unsigned hi = (unsigned)__builtin_amdgcn_update_dpp(0, (int)(unsigned)(k >> 32), CTRL, 0xF, 0xF, true);
  unsigned long long p = ((unsigned long long)hi << 32) | lo;
  return p > k ? p : k;
}

union ShU {
  struct { float4 pp[2][N_]; unsigned long long sw[2][2][4]; } f;  // fps(2 clouds)/knn view
  struct { __bf16 A[128 * AST]; __bf16 Bv[128 * AST]; } g;         // mlp view
};

// ---------------------------------------------------------------------------
__global__ __launch_bounds__(256) void fused_kernel(
    const float* __restrict__ pos, const float* __restrict__ x,
    const float* __restrict__ b1, const float* __restrict__ b2,
    const float* __restrict__ b3,
    const __bf16* __restrict__ w1t, const __bf16* __restrict__ w2t,
    const __bf16* __restrict__ w3t,
    int* __restrict__ ipub, int* __restrict__ ctr,
    float* __restrict__ out, float* __restrict__ pos_s) {
  __shared__ alignas(16) ShU sh;
  __shared__ int sh_item;
  const int tid = threadIdx.x;

  if (blockIdx.x < NFPSB) {
    // ========== FPS producer: 2 independent clouds, interleaved in-wave ==========
    __builtin_amdgcn_s_setprio(3);
    const int b0 = blockIdx.x * 2;
#pragma unroll
    for (int c = 0; c < 2; c++) {
      const float* pb = pos + (size_t)(b0 + c) * N_ * 3;
      for (int i = tid; i < N_; i += 256)
        sh.f.pp[c][i] = make_float4(pb[3 * i], pb[3 * i + 1], pb[3 * i + 2], 0.0f);
    }
    __syncthreads();

    f32x2 X2[2][8], Y2[2][8], Z2[2][8];
    float D[2][16];
    unsigned lo16[16];
    const unsigned ntid = ~(unsigned)tid;
#pragma unroll
    for (int j = 0; j < 8; j++) {
      lo16[2 * j]     = ntid - (unsigned)((2 * j) << 8);
      lo16[2 * j + 1] = ntid - (unsigned)((2 * j + 1) << 8);
#pragma unroll
      for (int c = 0; c < 2; c++) {
        float4 p0 = sh.f.pp[c][tid + ((2 * j) << 8)];
        float4 p1 = sh.f.pp[c][tid + ((2 * j + 1) << 8)];
        X2[c][j][0] = p0.x; X2[c][j][1] = p1.x;
        Y2[c][j][0] = p0.y; Y2[c][j][1] = p1.y;
        Z2[c][j][0] = p0.z; Z2[c][j][1] = p1.z;
        D[c][2 * j] = 1e30f; D[c][2 * j + 1] = 1e30f;
      }
    }

    float4 q[2] = { sh.f.pp[0][0], sh.f.pp[1][0] };
    if (tid == 0) {
#pragma unroll
      for (int c = 0; c < 2; c++) {
        __hip_atomic_store(ipub + (b0 + c) * M_, 1, __ATOMIC_RELAXED,
                           __HIP_MEMORY_SCOPE_AGENT);
        float* o = pos_s + (size_t)(b0 + c) * M_ * 3;
        o[0] = q[c].x; o[1] = q[c].y; o[2] = q[c].z;
      }
    }

    for (int i = 1; i < M_; i++) {
      unsigned long long kk[2];
#pragma unroll
      for (int c = 0; c < 2; c++) {
        f32x2 qx; qx[0] = q[c].x; qx[1] = q[c].x;
        f32x2 qy; qy[0] = q[c].y; qy[1] = q[c].y;
        f32x2 qz; qz[0] = q[c].z; qz[1] = q[c].z;
        unsigned long long key[16];
#pragma unroll
        for (int j = 0; j < 8; j++) {
          f32x2 dx = pk_sub(X2[c][j], qx);
          f32x2 dy = pk_sub(Y2[c][j], qy);
          f32x2 dz = pk_sub(Z2[c][j], qz);
          f32x2 t0 = pk_mul(dx, dx);
          f32x2 t1 = pk_mul(dy, dy);
          f32x2 s  = pk_add(t0, t1);
          f32x2 t2 = pk_mul(dz, dz);
          f32x2 d2 = pk_add(s, t2);
          D[c][2 * j]     = fminf(D[c][2 * j],     d2[0]);
          D[c][2 * j + 1] = fminf(D[c][2 * j + 1], d2[1]);
          key[2 * j]     = ((unsigned long long)__float_as_uint(D[c][2 * j])     << 32) | lo16[2 * j];
          key[2 * j + 1] = ((unsigned long long)__float_as_uint(D[c][2 * j + 1]) << 32) | lo16[2 * j + 1];
        }
#pragma unroll
        for (int s = 8; s > 0; s >>= 1)
#pragma unroll
          for (int k = 0; k < s; k++)
            if (key[k + s] > key[k]) key[k] = key[k + s];
        unsigned long long t = key[0];
        t = dpp_max_u64<0xB1>(t);    // quad_perm xor1
        t = dpp_max_u64<0x4E>(t);    // quad_perm xor2
        t = dpp_max_u64<0x141>(t);   // row_half_mirror (xor4)
        t = dpp_max_u64<0x140>(t);   // row_mirror (xor8)
        t = dpp_max_u64<0x142>(t);   // row_bcast15
        t = dpp_max_u64<0x143>(t);   // row_bcast31
        kk[c] = t;
      }

      const int par = i & 1;
      if ((tid & 63) == 63) {
        sh.f.sw[0][par][tid >> 6] = kk[0];
        sh.f.sw[1][par][tid >> 6] = kk[1];
      }
      __syncthreads();

      int cur[2];
#pragma unroll
      for (int c = 0; c < 2; c++) {
        const ulonglong2 v01 = *(const ulonglong2*)&sh.f.sw[c][par][0];
        const ulonglong2 v23 = *(const ulonglong2*)&sh.f.sw[c][par][2];
        const int c0 = (int)(~(unsigned)v01.x), c1 = (int)(~(unsigned)v01.y);
        const int c2 = (int)(~(unsigned)v23.x), c3 = (int)(~(unsigned)v23.y);
        float4 q0 = sh.f.pp[c][c0], q1 = sh.f.pp[c][c1];
        float4 q2 = sh.f.pp[c][c2], q3 = sh.f.pp[c][c3];
        unsigned long long k01, k23; float4 q01, q23; int i01, i23;
        if (v01.y > v01.x) { k01 = v01.y; q01 = q1; i01 = c1; }
        else               { k01 = v01.x; q01 = q0; i01 = c0; }
        if (v23.y > v23.x) { k23 = v23.y; q23 = q3; i23 = c3; }
        else               { k23 = v23.x; q23 = q2; i23 = c2; }
        if (k23 > k01) { q[c] = q23; cur[c] = i23; }
        else           { q[c] = q01; cur[c] = i01; }
      }

      if (tid == 0) {
#pragma unroll
        for (int c = 0; c < 2; c++) {
          __hip_atomic_store(ipub + (b0 + c) * M_ + i, cur[c] + 1, __ATOMIC_RELAXED,
                             __HIP_MEMORY_SCOPE_AGENT);   // datum == flag
          float* o = pos_s + ((size_t)(b0 + c) * M_ + i) * 3;
          o[0] = q[c].x; o[1] = q[c].y; o[2] = q[c].z;
        }
      }
    }
    return;
  }

  // ================= persistent worker: kNN + MLP per item =================
  const int w    = tid >> 6;
  const int lane = tid & 63;

  for (;;) {
    if (tid == 0) sh_item = atomicAdd(ctr, 1);
    __syncthreads();
    const int it = sh_item;
    if (it >= NITEM) return;
    const int b    = it & 15;
    const int mset = it >> 4;
    const int m    = mset * 4 + w;

    __syncthreads();   // previous item's LDS reads complete before restage
    {
      const float* pb = pos + (size_t)b * N_ * 3;
      for (int i = tid; i < N_; i += 256)
        sh.f.pp[0][i] = make_float4(pb[3 * i], pb[3 * i + 1], pb[3 * i + 2], 0.0f);
    }
    __syncthreads();   // staging visible to all waves

    // per-wave poll of its own published index (relaxed agent load)
    int ci0 = 0;
    if (lane == 0) {
      int v;
      while ((v = __hip_atomic_load(ipub + b * M_ + m, __ATOMIC_RELAXED,
                                    __HIP_MEMORY_SCOPE_AGENT)) == 0)
        __builtin_amdgcn_s_sleep(8);
      ci0 = v - 1;
    }
    const int ci = __shfl(ci0, 0);
    const float4 c = sh.f.pp[0][ci];

    // ---- kNN pass A: distances + lane-min key ----
    float d2v[64];
    unsigned long long kmin = ~0ull;
#pragma unroll
    for (int t = 0; t < 64; t++) {
      const int j = t * 64 + lane;
      const float4 p = sh.f.pp[0][j];
      float dx = __fsub_rn(p.x, c.x);
      float dy = __fsub_rn(p.y, c.y);
      float dz = __fsub_rn(p.z, c.z);
      float d  = __fadd_rn(__fadd_rn(__fmul_rn(dx, dx), __fmul_rn(dy, dy)),
                           __fmul_rn(dz, dz));
      d2v[t] = d;
      const unsigned long long k64 =
          ((unsigned long long)__float_as_uint(d) << 32) | (unsigned int)j;
      if (k64 < kmin) kmin = k64;
    }

    // ---- bitonic sort of lane-min keys; seed top-32; threshold T0 ----
    unsigned long long sk = kmin;
#pragma unroll
    for (int size = 2; size <= 64; size <<= 1) {
#pragma unroll
      for (int stride = size >> 1; stride > 0; stride >>= 1) {
        const unsigned long long other = __shfl_xor(sk, stride);
        const bool up      = ((lane & size) == 0);
        const bool lowhalf = ((lane & stride) == 0);
        const bool takeMin = (up == lowhalf);
        const bool swp     = takeMin ? (other < sk) : (other > sk);
        if (swp) sk = other;
      }
    }
    const unsigned long long T0 = __shfl(sk, 31);
    const bool seeded = (kmin <= T0);

    unsigned long long rkey = (lane < 32) ? sk : ~0ull;
    unsigned long long wk   = T0;

    // ---- pass B: scan, skipping seeded keys ----
#pragma unroll
    for (int t = 0; t < 64; t++) {
      const int j = t * 64 + lane;
      const unsigned long long k64 =
          ((unsigned long long)__float_as_uint(d2v[t]) << 32) | (unsigned int)j;
      const bool skip = seeded && (k64 == kmin);
      unsigned long long mask = __ballot((k64 < wk) && !skip);
      if (mask) {
        while (mask) {
          const int src = __ffsll((unsigned long long)mask) - 1;
          mask &= mask - 1;
          const unsigned long long cand = __shfl(k64, src);
          const int pos_i = (int)__popcll(__ballot(rkey < cand));  // >=32 -> no-op
          const unsigned long long sh_ = __shfl_up(rkey, 1);
          if (lane < 32) {
            if (lane == pos_i)      rkey = cand;
            else if (lane > pos_i)  rkey = sh_;
          }
        }
        wk = __shfl(rkey, 31);
      }
    }
    const int njl = (int)(rkey & 0xFFFFull);   // valid in lanes 0..31
    __syncthreads();   // all pp reads done before mlp buffers alias it

    // ---- gather: wave w fills rows [32w,32w+32) for its centroid ----
    {
      const int rl   = lane >> 1;
      const int half = lane & 1;
      const int r    = w * 32 + rl;
      const int nj   = __shfl(njl, rl);
      const float4* xr = (const float4*)(x + ((size_t)(b * N_ + nj)) * 64 + half * 32);
      __bf16* dst = &sh.g.A[r * AST + half * 32];
#pragma unroll
      for (int t = 0; t < 8; t++) {
        float4 v = xr[t];
        bf16x4 u;
        u[0] = (__bf16)v.x; u[1] = (__bf16)v.y; u[2] = (__bf16)v.z; u[3] = (__bf16)v.w;
        *(bf16x4*)(dst + t * 4) = u;
      }
      bf16x8 z;
#pragma unroll
      for (int q2 = 0; q2 < 8; q2++) z[q2] = (__bf16)0.0f;
      if (half == 0) {
        const float* pj = pos + ((size_t)(b * N_ + nj)) * 3;
        bf16x8 u = z;
        u[0] = (__bf16)(pj[0] - c.x);
        u[1] = (__bf16)(pj[1] - c.y);
        u[2] = (__bf16)(pj[2] - c.z);
        *(bf16x8*)&sh.g.A[r * AST + 64] = u;
        *(bf16x8*)&sh.g.A[r * AST + 72] = z;
      } else {
        *(bf16x8*)&sh.g.A[r * AST + 80] = z;
        *(bf16x8*)&sh.g.A[r * AST + 88] = z;
      }
    }
    __syncthreads();

    const int lrow = lane & 15;
    const int lk8  = (lane >> 4) << 3;
    const int orow = (lane >> 4) << 2;

    // ---- L1: msg(96) @ W1 -> relu -> Bv. Wave w: cols [32w,32w+32) ----
    {
      f32x4 acc[8][2];
#pragma unroll
      for (int n = 0; n < 2; n++) {
        const float bv = b1[(2 * w + n) * 16 + lrow];
        f32x4 a = {bv, bv, bv, bv};
#pragma unroll
        for (int rt = 0; rt < 8; rt++) acc[rt][n] = a;
      }
#pragma unroll
      for (int s = 0; s < 3; s++) {
        bf16x8 a[8];
#pragma unroll
        for (int rt = 0; rt < 8; rt++)
          a[rt] = *(const bf16x8*)&sh.g.A[(rt * 16 + lrow) * AST + s * 32 + lk8];
#pragma unroll
        for (int n = 0; n < 2; n++) {
          bf16x8 bb = *(const bf16x8*)&w1t[((2 * w + n) * 16 + lrow) * 96 + s * 32 + lk8];
#pragma unroll
          for (int rt = 0; rt < 8; rt++)
            acc[rt][n] = __builtin_amdgcn_mfma_f32_16x16x32_bf16(a[rt], bb, acc[rt][n], 0, 0, 0);
        }
      }
      __syncthreads();
#pragma unroll
      for (int n = 0; n < 2; n++)
#pragma unroll
        for (int rt = 0; rt < 8; rt++)
#pragma unroll
          for (int j = 0; j < 4; j++)
            sh.g.Bv[(rt * 16 + orow + j) * AST + (2 * w + n) * 16 + lrow] =
                (__bf16)fmaxf(acc[rt][n][j], 0.0f);
    }
    __syncthreads();

    // ---- L2: Bv(128) @ W2 -> relu -> A ----
    {
      f32x4 acc[8][2];
#pragma unroll
      for (int n = 0; n < 2; n++) {
        const float bv = b2[(2 * w + n) * 16 + lrow];
        f32x4 a = {bv, bv, bv, bv};
#pragma unroll
        for (int rt = 0; rt < 8; rt++) acc[rt][n] = a;
      }
#pragma unroll
      for (int s = 0; s < 4; s++) {
        bf16x8 a[8];
#pragma unroll
        for (int rt = 0; rt < 8; rt++)
          a[rt] = *(const bf16x8*)&sh.g.Bv[(rt * 16 + lrow) * AST + s * 32 + lk8];
#pragma unroll
        for (int n = 0; n < 2; n++) {
          bf16x8 bb = *(const bf16x8*)&w2t[((2 * w + n) * 16 + lrow) * 128 + s * 32 + lk8];
#pragma unroll
          for (int rt = 0; rt < 8; rt++)
            acc[rt][n] = __builtin_amdgcn_mfma_f32_16x16x32_bf16(a[rt], bb, acc[rt][n], 0, 0, 0);
        }
      }
      __syncthreads();
#pragma unroll
      for (int n = 0; n < 2; n++)
#pragma unroll
        for (int rt = 0; rt < 8; rt++)
#pragma unroll
          for (int j = 0; j < 4; j++)
            sh.g.A[(rt * 16 + orow + j) * AST + (2 * w + n) * 16 + lrow] =
                (__bf16)fmaxf(acc[rt][n][j], 0.0f);
    }
    __syncthreads();

    // ---- L3 + maxpool. Wave w: cols [64w,64w+64) in two passes ----
#pragma unroll
    for (int np = 0; np < 2; np++) {
      f32x4 acc[8][2];
#pragma unroll
      for (int n = 0; n < 2; n++) {
        const float bv = b3[(4 * w + 2 * np + n) * 16 + lrow];
        f32x4 a = {bv, bv, bv, bv};
#pragma unroll
        for (int rt = 0; rt < 8; rt++) acc[rt][n] = a;
      }
#pragma unroll
      for (int s = 0; s < 4; s++) {
        bf16x8 a[8];
#pragma unroll
        for (int rt = 0; rt < 8; rt++)
          a[rt] = *(const bf16x8*)&sh.g.A[(rt * 16 + lrow) * AST + s * 32 + lk8];
#pragma unroll
        for (int n = 0; n < 2; n++) {
          bf16x8 bb = *(const bf16x8*)&w3t[((4 * w + 2 * np + n) * 16 + lrow) * 128 + s * 32 + lk8];
#pragma unroll
          for (int rt = 0; rt < 8; rt++)
            acc[rt][n] = __builtin_amdgcn_mfma_f32_16x16x32_bf16(a[rt], bb, acc[rt][n], 0, 0, 0);
        }
      }
#pragma unroll
      for (int ccc = 0; ccc < 4; ccc++) {
#pragma unroll
        for (int n = 0; n < 2; n++) {
          f32x4 a0 = acc[2 * ccc][n], a1 = acc[2 * ccc + 1][n];
          float v = fmaxf(fmaxf(fmaxf(a0[0], a0[1]), fmaxf(a0[2], a0[3])),
                          fmaxf(fmaxf(a1[0], a1[1]), fmaxf(a1[2], a1[3])));
          v = fmaxf(v, __shfl_xor(v, 16));
          v = fmaxf(v, __shfl_xor(v, 32));
          v = fmaxf(v, 0.0f);
          if (lane < 16)
            out[((size_t)(b * M_ + mset * 4 + ccc)) * 256 + (4 * w + 2 * np + n) * 16 + lane] = v;
        }
      }
    }
    // loop to next item
  }
}

// ---------------------------------------------------------------------------
extern "C" void kernel_launch(void* const* d_in, const int* in_sizes, int n_in,
                              void* d_out, int out_size, void* d_ws, size_t ws_size,
                              hipStream_t stream) {
  const float* x   = (const float*)d_in[0];
  const float* pos = (const float*)d_in[1];
  const float* W1  = (const float*)d_in[2];
  const float* b1  = (const float*)d_in[3];
  const float* W2  = (const float*)d_in[4];
  const float* b2  = (const float*)d_in[5];
  const float* W3  = (const float*)d_in[6];
  const float* b3  = (const float*)d_in[7];

  float* out   = (float*)d_out;
  float* pos_s = out + (size_t)B_ * M_ * 256;

  char* ws = (char*)d_ws;
  int*    ipub = (int*)ws;                        // 65536 B: published idx+1
  int*    ctr  = (int*)(ws + 65536);              // 4 B
  __bf16* w1t  = (__bf16*)(ws + 65792);           // 24576 B
  __bf16* w2t  = (__bf16*)(ws + 90368);           // 32768 B
  __bf16* w3t  = (__bf16*)(ws + 123136);          // 65536 B

  hipMemsetAsync(ws, 0, 65540, stream);           // ipub + ctr
  prep_weights<<<dim3(128), dim3(256), 0, stream>>>(W1, W2, W3, w1t, w2t, w3t);
  fused_kernel<<<dim3(NFPSB + NWORK), dim3(256), 0, stream>>>(
      pos, x, b1, b2, b3, w1t, w2t, w3t, ipub, ctr, out, pos_s);
}

// Round 10
// 745.008 us; speedup vs baseline: 1.6844x; 1.6844x over previous
//
#include <hip/hip_runtime.h>

// SAModule (PointNet++): FPS -> kNN(32) -> [x||rel] MLP(67->128->128->256) -> max over K.
// B=16, N=4096, C=64, M=1024, K=32.
// R9: FPS argmax restructured as value-first (f32 max tree + f32 DPP) with a
// rare-wave index-resolution phase (equality chain + LDS atomicMin, exact
// first-occurrence ties). Cuts ~100 VALU inst/iter of u64-key machinery at
// the cost of a second block barrier. Workers = R7 (fence-free ipub).
// R8 lesson: FPS is issue-bound; win by fewer instructions, not more ILP.

#define B_    16
#define N_    4096
#define M_    1024
#define AST   136
#define NWORK 240
#define NITEM (256 * 16)   // items ordered mset-major: it = mset*16 + b

typedef __bf16 bf16x8 __attribute__((ext_vector_type(8)));
typedef __bf16 bf16x4 __attribute__((ext_vector_type(4)));
typedef float  f32x4  __attribute__((ext_vector_type(4)));
typedef float  f32x2  __attribute__((ext_vector_type(2)));

// ---------------------------------------------------------------------------
// Weight prep: transpose + cast to bf16, pad W1 K-dim 67->96 with zeros.
// ---------------------------------------------------------------------------
__global__ __launch_bounds__(256) void prep_weights(
    const float* __restrict__ W1, const float* __restrict__ W2,
    const float* __restrict__ W3,
    __bf16* __restrict__ w1t, __bf16* __restrict__ w2t, __bf16* __restrict__ w3t) {
  const int t = blockIdx.x * 256 + threadIdx.x;   // 0..32767
  if (t < 128 * 96) {
    const int n = t / 96, k = t % 96;
    w1t[t] = (k < 67) ? (__bf16)W1[k * 128 + n] : (__bf16)0.0f;
  }
  if (t < 128 * 128) {
    const int n = t >> 7, k = t & 127;
    w2t[t] = (__bf16)W2[k * 128 + n];
  }
  {
    const int n = t >> 7, k = t & 127;   // t < 256*128 always
    w3t[t] = (__bf16)W3[k * 256 + n];
  }
}

// ---------------------------------------------------------------------------
__device__ __forceinline__ f32x2 pk_sub(f32x2 a, f32x2 b) {
  f32x2 d;
  asm("v_pk_add_f32 %0, %1, %2 neg_lo:[0,1] neg_hi:[0,1]" : "=v"(d) : "v"(a), "v"(b));
  return d;
}
__device__ __forceinline__ f32x2 pk_mul(f32x2 a, f32x2 b) {
  f32x2 d;
  asm("v_pk_mul_f32 %0, %1, %2" : "=v"(d) : "v"(a), "v"(b));
  return d;
}
__device__ __forceinline__ f32x2 pk_add(f32x2 a, f32x2 b) {
  f32x2 d;
  asm("v_pk_add_f32 %0, %1, %2" : "=v"(d) : "v"(a), "v"(b));
  return d;
}

template <int CTRL>
__device__ __forceinline__ float dpp_max_f32(float v) {
  int t = __builtin_amdgcn_update_dpp(0, __float_as_int(v), CTRL, 0xF, 0xF, true);
  return fmaxf(v, __int_as_float(t));   // D >= 0, 0-fill always loses/ties-safe
}

union ShU {
  struct {
    float4 pp[N_];
    alignas(16) float swv[2][4];   // per-wave value maxes (parity)
    unsigned slot[2];              // argmax idx via atomicMin (parity)
  } f;                                                       // fps / knn view
  struct { __bf16 A[128 * AST]; __bf16 Bv[128 * AST]; } g;   // mlp view
};

// ---------------------------------------------------------------------------
__global__ __launch_bounds__(256) void fused_kernel(
    const float* __restrict__ pos, const float* __restrict__ x,
    const float* __restrict__ b1, const float* __restrict__ b2,
    const float* __restrict__ b3,
    const __bf16* __restrict__ w1t, const __bf16* __restrict__ w2t,
    const __bf16* __restrict__ w3t,
    int* __restrict__ ipub, int* __restrict__ ctr,
    float* __restrict__ out, float* __restrict__ pos_s) {
  __shared__ alignas(16) ShU sh;
  __shared__ int sh_item;
  const int tid = threadIdx.x;

  if (blockIdx.x < B_) {
    // ========== FPS producer: value-first argmax, two light barriers ==========
    __builtin_amdgcn_s_setprio(3);
    const int b = blockIdx.x;
    const float* pb = pos + (size_t)b * N_ * 3;
    for (int i = tid; i < N_; i += 256)
      sh.f.pp[i] = make_float4(pb[3 * i], pb[3 * i + 1], pb[3 * i + 2], 0.0f);
    if (tid == 0) { sh.f.slot[0] = 0xFFFFFFFFu; sh.f.slot[1] = 0xFFFFFFFFu; }
    __syncthreads();

    f32x2 X2[8], Y2[8], Z2[8];
    float D[16];
#pragma unroll
    for (int j = 0; j < 8; j++) {
      float4 p0 = sh.f.pp[tid + ((2 * j) << 8)];
      float4 p1 = sh.f.pp[tid + ((2 * j + 1) << 8)];
      X2[j][0] = p0.x; X2[j][1] = p1.x;
      Y2[j][0] = p0.y; Y2[j][1] = p1.y;
      Z2[j][0] = p0.z; Z2[j][1] = p1.z;
      D[2 * j] = 1e30f; D[2 * j + 1] = 1e30f;
    }

    float4 q = sh.f.pp[0];
    if (tid == 0) {
      __hip_atomic_store(ipub + b * M_, 1, __ATOMIC_RELAXED,
                         __HIP_MEMORY_SCOPE_AGENT);
      float* o = pos_s + (size_t)b * M_ * 3;
      o[0] = q.x; o[1] = q.y; o[2] = q.z;
    }

    for (int i = 1; i < M_; i++) {
      const int par = i & 1;
      // ---- distances (packed, exact ((dx^2+dy^2)+dz^2) order) + min update ----
      f32x2 qx; qx[0] = q.x; qx[1] = q.x;
      f32x2 qy; qy[0] = q.y; qy[1] = q.y;
      f32x2 qz; qz[0] = q.z; qz[1] = q.z;
#pragma unroll
      for (int j = 0; j < 8; j++) {
        f32x2 dx = pk_sub(X2[j], qx);
        f32x2 dy = pk_sub(Y2[j], qy);
        f32x2 dz = pk_sub(Z2[j], qz);
        f32x2 t0 = pk_mul(dx, dx);
        f32x2 t1 = pk_mul(dy, dy);
        f32x2 s  = pk_add(t0, t1);
        f32x2 t2 = pk_mul(dz, dz);
        f32x2 d2 = pk_add(s, t2);
        D[2 * j]     = fminf(D[2 * j],     d2[0]);
        D[2 * j + 1] = fminf(D[2 * j + 1], d2[1]);
      }
      // ---- per-thread value max (balanced tree; folds to v_max3) ----
      float m0 = fmaxf(fmaxf(fmaxf(D[0], D[1]), fmaxf(D[2], D[3])),
                       fmaxf(fmaxf(D[4], D[5]), fmaxf(D[6], D[7])));
      float m1 = fmaxf(fmaxf(fmaxf(D[8], D[9]), fmaxf(D[10], D[11])),
                       fmaxf(fmaxf(D[12], D[13]), fmaxf(D[14], D[15])));
      const float tv = fmaxf(m0, m1);

      // ---- wave value max on VALU pipe (lane 63 holds it) ----
      float wv = tv;
      wv = dpp_max_f32<0xB1>(wv);    // quad_perm xor1
      wv = dpp_max_f32<0x4E>(wv);    // quad_perm xor2
      wv = dpp_max_f32<0x141>(wv);   // row_half_mirror
      wv = dpp_max_f32<0x140>(wv);   // row_mirror
      wv = dpp_max_f32<0x142>(wv);   // row_bcast15
      wv = dpp_max_f32<0x143>(wv);   // row_bcast31
      if ((tid & 63) == 63) sh.f.swv[par][tid >> 6] = wv;
      __syncthreads();   // B1

      const float4 mv4 = *(const float4*)&sh.f.swv[par][0];
      const float mv = fmaxf(fmaxf(mv4.x, mv4.y), fmaxf(mv4.z, mv4.w));

      // ---- index resolution: only the wave(s) containing mv do the chain ----
      if (__any(tv == mv)) {
        unsigned gidx = 0xFFFFFFFFu;
#pragma unroll
        for (int k = 15; k >= 0; k--)          // descending => smallest k wins
          if (D[k] == mv) gidx = (unsigned)(tid + (k << 8));
        if (gidx != 0xFFFFFFFFu)
          atomicMin(&sh.f.slot[par], gidx);    // min global idx == first occurrence
      }
      __syncthreads();   // B2

      const int cur = (int)sh.f.slot[par];
      if (tid == 0) sh.f.slot[par ^ 1] = 0xFFFFFFFFu;  // reset other parity
      q = sh.f.pp[cur];
      if (tid == 0) {
        __hip_atomic_store(ipub + b * M_ + i, cur + 1, __ATOMIC_RELAXED,
                           __HIP_MEMORY_SCOPE_AGENT);   // datum == flag
        float* o = pos_s + ((size_t)b * M_ + i) * 3;
        o[0] = q.x; o[1] = q.y; o[2] = q.z;
      }
    }
    return;
  }

  // ================= persistent worker: kNN + MLP per item =================
  const int w    = tid >> 6;
  const int lane = tid & 63;

  for (;;) {
    if (tid == 0) sh_item = atomicAdd(ctr, 1);
    __syncthreads();
    const int it = sh_item;
    if (it >= NITEM) return;
    const int b    = it & 15;
    const int mset = it >> 4;
    const int m    = mset * 4 + w;

    __syncthreads();   // previous item's LDS reads complete before restage
    {
      const float* pb = pos + (size_t)b * N_ * 3;
      for (int i = tid; i < N_; i += 256)
        sh.f.pp[i] = make_float4(pb[3 * i], pb[3 * i + 1], pb[3 * i + 2], 0.0f);
    }
    __syncthreads();   // staging visible to all waves

    // per-wave poll of its own published index (relaxed agent load)
    int ci0 = 0;
    if (lane == 0) {
      int v;
      while ((v = __hip_atomic_load(ipub + b * M_ + m, __ATOMIC_RELAXED,
                                    __HIP_MEMORY_SCOPE_AGENT)) == 0)
        __builtin_amdgcn_s_sleep(8);
      ci0 = v - 1;
    }
    const int ci = __shfl(ci0, 0);
    const float4 c = sh.f.pp[ci];

    // ---- kNN pass A: distances + lane-min key ----
    float d2v[64];
    unsigned long long kmin = ~0ull;
#pragma unroll
    for (int t = 0; t < 64; t++) {
      const int j = t * 64 + lane;
      const float4 p = sh.f.pp[j];
      float dx = __fsub_rn(p.x, c.x);
      float dy = __fsub_rn(p.y, c.y);
      float dz = __fsub_rn(p.z, c.z);
      float d  = __fadd_rn(__fadd_rn(__fmul_rn(dx, dx), __fmul_rn(dy, dy)),
                           __fmul_rn(dz, dz));
      d2v[t] = d;
      const unsigned long long k64 =
          ((unsigned long long)__float_as_uint(d) << 32) | (unsigned int)j;
      if (k64 < kmin) kmin = k64;
    }

    // ---- bitonic sort of lane-min keys; seed top-32; threshold T0 ----
    unsigned long long sk = kmin;
#pragma unroll
    for (int size = 2; size <= 64; size <<= 1) {
#pragma unroll
      for (int stride = size >> 1; stride > 0; stride >>= 1) {
        const unsigned long long other = __shfl_xor(sk, stride);
        const bool up      = ((lane & size) == 0);
        const bool lowhalf = ((lane & stride) == 0);
        const bool takeMin = (up == lowhalf);
        const bool swp     = takeMin ? (other < sk) : (other > sk);
        if (swp) sk = other;
      }
    }
    const unsigned long long T0 = __shfl(sk, 31);
    const bool seeded = (kmin <= T0);

    unsigned long long rkey = (lane < 32) ? sk : ~0ull;
    unsigned long long wk   = T0;

    // ---- pass B: scan, skipping seeded keys ----
#pragma unroll
    for (int t = 0; t < 64; t++) {
      const int j = t * 64 + lane;
      const unsigned long long k64 =
          ((unsigned long long)__float_as_uint(d2v[t]) << 32) | (unsigned int)j;
      const bool skip = seeded && (k64 == kmin);
      unsigned long long mask = __ballot((k64 < wk) && !skip);
      if (mask) {
        while (mask) {
          const int src = __ffsll((unsigned long long)mask) - 1;
          mask &= mask - 1;
          const unsigned long long cand = __shfl(k64, src);
          const int pos_i = (int)__popcll(__ballot(rkey < cand));  // >=32 -> no-op
          const unsigned long long sh_ = __shfl_up(rkey, 1);
          if (lane < 32) {
            if (lane == pos_i)      rkey = cand;
            else if (lane > pos_i)  rkey = sh_;
          }
        }
        wk = __shfl(rkey, 31);
      }
    }
    const int njl = (int)(rkey & 0xFFFFull);   // valid in lanes 0..31
    __syncthreads();   // all pp reads done before mlp buffers alias it

    // ---- gather: wave w fills rows [32w,32w+32) for its centroid ----
    {
      const int rl   = lane >> 1;
      const int half = lane & 1;
      const int r    = w * 32 + rl;
      const int nj   = __shfl(njl, rl);
      const float4* xr = (const float4*)(x + ((size_t)(b * N_ + nj)) * 64 + half * 32);
      __bf16* dst = &sh.g.A[r * AST + half * 32];
#pragma unroll
      for (int t = 0; t < 8; t++) {
        float4 v = xr[t];
        bf16x4 u;
        u[0] = (__bf16)v.x; u[1] = (__bf16)v.y; u[2] = (__bf16)v.z; u[3] = (__bf16)v.w;
        *(bf16x4*)(dst + t * 4) = u;
      }
      bf16x8 z;
#pragma unroll
      for (int q2 = 0; q2 < 8; q2++) z[q2] = (__bf16)0.0f;
      if (half == 0) {
        const float* pj = pos + ((size_t)(b * N_ + nj)) * 3;
        bf16x8 u = z;
        u[0] = (__bf16)(pj[0] - c.x);
        u[1] = (__bf16)(pj[1] - c.y);
        u[2] = (__bf16)(pj[2] - c.z);
        *(bf16x8*)&sh.g.A[r * AST + 64] = u;
        *(bf16x8*)&sh.g.A[r * AST + 72] = z;
      } else {
        *(bf16x8*)&sh.g.A[r * AST + 80] = z;
        *(bf16x8*)&sh.g.A[r * AST + 88] = z;
      }
    }
    __syncthreads();

    const int lrow = lane & 15;
    const int lk8  = (lane >> 4) << 3;
    const int orow = (lane >> 4) << 2;

    // ---- L1: msg(96) @ W1 -> relu -> Bv. Wave w: cols [32w,32w+32) ----
    {
      f32x4 acc[8][2];
#pragma unroll
      for (int n = 0; n < 2; n++) {
        const float bv = b1[(2 * w + n) * 16 + lrow];
        f32x4 a = {bv, bv, bv, bv};
#pragma unroll
        for (int rt = 0; rt < 8; rt++) acc[rt][n] = a;
      }
#pragma unroll
      for (int s = 0; s < 3; s++) {
        bf16x8 a[8];
#pragma unroll
        for (int rt = 0; rt < 8; rt++)
          a[rt] = *(const bf16x8*)&sh.g.A[(rt * 16 + lrow) * AST + s * 32 + lk8];
#pragma unroll
        for (int n = 0; n < 2; n++) {
          bf16x8 bb = *(const bf16x8*)&w1t[((2 * w + n) * 16 + lrow) * 96 + s * 32 + lk8];
#pragma unroll
          for (int rt = 0; rt < 8; rt++)
            acc[rt][n] = __builtin_amdgcn_mfma_f32_16x16x32_bf16(a[rt], bb, acc[rt][n], 0, 0, 0);
        }
      }
      __syncthreads();
#pragma unroll
      for (int n = 0; n < 2; n++)
#pragma unroll
        for (int rt = 0; rt < 8; rt++)
#pragma unroll
          for (int j = 0; j < 4; j++)
            sh.g.Bv[(rt * 16 + orow + j) * AST + (2 * w + n) * 16 + lrow] =
                (__bf16)fmaxf(acc[rt][n][j], 0.0f);
    }
    __syncthreads();

    // ---- L2: Bv(128) @ W2 -> relu -> A ----
    {
      f32x4 acc[8][2];
#pragma unroll
      for (int n = 0; n < 2; n++) {
        const float bv = b2[(2 * w + n) * 16 + lrow];
        f32x4 a = {bv, bv, bv, bv};
#pragma unroll
        for (int rt = 0; rt < 8; rt++) acc[rt][n] = a;
      }
#pragma unroll
      for (int s = 0; s < 4; s++) {
        bf16x8 a[8];
#pragma unroll
        for (int rt = 0; rt < 8; rt++)
          a[rt] = *(const bf16x8*)&sh.g.Bv[(rt * 16 + lrow) * AST + s * 32 + lk8];
#pragma unroll
        for (int n = 0; n < 2; n++) {
          bf16x8 bb = *(const bf16x8*)&w2t[((2 * w + n) * 16 + lrow) * 128 + s * 32 + lk8];
#pragma unroll
          for (int rt = 0; rt < 8; rt++)
            acc[rt][n] = __builtin_amdgcn_mfma_f32_16x16x32_bf16(a[rt], bb, acc[rt][n], 0, 0, 0);
        }
      }
      __syncthreads();
#pragma unroll
      for (int n = 0; n < 2; n++)
#pragma unroll
        for (int rt = 0; rt < 8; rt++)
#pragma unroll
          for (int j = 0; j < 4; j++)
            sh.g.A[(rt * 16 + orow + j) * AST + (2 * w + n) * 16 + lrow] =
                (__bf16)fmaxf(acc[rt][n][j], 0.0f);
    }
    __syncthreads();

    // ---- L3 + maxpool. Wave w: cols [64w,64w+64) in two passes ----
#pragma unroll
    for (int np = 0; np < 2; np++) {
      f32x4 acc[8][2];
#pragma unroll
      for (int n = 0; n < 2; n++) {
        const float bv = b3[(4 * w + 2 * np + n) * 16 + lrow];
        f32x4 a = {bv, bv, bv, bv};
#pragma unroll
        for (int rt = 0; rt < 8; rt++) acc[rt][n] = a;
      }
#pragma unroll
      for (int s = 0; s < 4; s++) {
        bf16x8 a[8];
#pragma unroll
        for (int rt = 0; rt < 8; rt++)
          a[rt] = *(const bf16x8*)&sh.g.A[(rt * 16 + lrow) * AST + s * 32 + lk8];
#pragma unroll
        for (int n = 0; n < 2; n++) {
          bf16x8 bb = *(const bf16x8*)&w3t[((4 * w + 2 * np + n) * 16 + lrow) * 128 + s * 32 + lk8];
#pragma unroll
          for (int rt = 0; rt < 8; rt++)
            acc[rt][n] = __builtin_amdgcn_mfma_f32_16x16x32_bf16(a[rt], bb, acc[rt][n], 0, 0, 0);
        }
      }
#pragma unroll
      for (int ccc = 0; ccc < 4; ccc++) {
#pragma unroll
        for (int n = 0; n < 2; n++) {
          f32x4 a0 = acc[2 * ccc][n], a1 = acc[2 * ccc + 1][n];
          float v = fmaxf(fmaxf(fmaxf(a0[0], a0[1]), fmaxf(a0[2], a0[3])),
                          fmaxf(fmaxf(a1[0], a1[1]), fmaxf(a1[2], a1[3])));
          v = fmaxf(v, __shfl_xor(v, 16));
          v = fmaxf(v, __shfl_xor(v, 32));
          v = fmaxf(v, 0.0f);
          if (lane < 16)
            out[((size_t)(b * M_ + mset * 4 + ccc)) * 256 + (4 * w + 2 * np + n) * 16 + lane] = v;
        }
      }
    }
    // loop to next item
  }
}

// ---------------------------------------------------------------------------
extern "C" void kernel_launch(void* const* d_in, const int* in_sizes, int n_in,
                              void* d_out, int out_size, void* d_ws, size_t ws_size,
                              hipStream_t stream) {
  const float* x   = (const float*)d_in[0];
  const float* pos = (const float*)d_in[1];
  const float* W1  = (const float*)d_in[2];
  const float* b1  = (const float*)d_in[3];
  const float* W2  = (const float*)d_in[4];
  const float* b2  = (const float*)d_in[5];
  const float* W3  = (const float*)d_in[6];
  const float* b3  = (const float*)d_in[7];

  float* out   = (float*)d_out;
  float* pos_s = out + (size_t)B_ * M_ * 256;

  char* ws = (char*)d_ws;
  int*    ipub = (int*)ws;                        // 65536 B: published idx+1
  int*    ctr  = (int*)(ws + 65536);              // 4 B
  __bf16* w1t  = (__bf16*)(ws + 65792);           // 24576 B
  __bf16* w2t  = (__bf16*)(ws + 90368);           // 32768 B
  __bf16* w3t  = (__bf16*)(ws + 123136);          // 65536 B

  hipMemsetAsync(ws, 0, 65540, stream);           // ipub + ctr
  prep_weights<<<dim3(128), dim3(256), 0, stream>>>(W1, W2, W3, w1t, w2t, w3t);
  fused_kernel<<<dim3(B_ + NWORK), dim3(256), 0, stream>>>(
      pos, x, b1, b2, b3, w1t, w2t, w3t, ipub, ctr, out, pos_s);
}

// Round 11
// 664.588 us; speedup vs baseline: 1.8882x; 1.1210x over previous
//
#include <hip/hip_runtime.h>

// SAModule (PointNet++): FPS -> kNN(32) -> [x||rel] MLP(67->128->128->256) -> max over K.
// B=16, N=4096, C=64, M=1024, K=32.
// R10 = R7 (best: 666.5us) + one change: FPS's per-iteration __syncthreads()
// replaced by {s_waitcnt lgkmcnt(0); raw s_barrier}. __syncthreads() emits
// s_waitcnt vmcnt(0) before s_barrier, so tid0's 4 fire-and-forget global
// stores (ipub publish + pos_s) were drained to L2 on the block critical path
// EVERY iteration (~200-300cyc). Cross-wave exchange only needs lgkmcnt.
// R9 lesson (reverted): extra barriers cost more than saved VALU ops.

#define B_    16
#define N_    4096
#define M_    1024
#define AST   136
#define NWORK 240
#define NITEM (256 * 16)   // items ordered mset-major: it = mset*16 + b

typedef __bf16 bf16x8 __attribute__((ext_vector_type(8)));
typedef __bf16 bf16x4 __attribute__((ext_vector_type(4)));
typedef float  f32x4  __attribute__((ext_vector_type(4)));
typedef float  f32x2  __attribute__((ext_vector_type(2)));

// ---------------------------------------------------------------------------
// Weight prep: transpose + cast to bf16, pad W1 K-dim 67->96 with zeros.
// ---------------------------------------------------------------------------
__global__ __launch_bounds__(256) void prep_weights(
    const float* __restrict__ W1, const float* __restrict__ W2,
    const float* __restrict__ W3,
    __bf16* __restrict__ w1t, __bf16* __restrict__ w2t, __bf16* __restrict__ w3t) {
  const int t = blockIdx.x * 256 + threadIdx.x;   // 0..32767
  if (t < 128 * 96) {
    const int n = t / 96, k = t % 96;
    w1t[t] = (k < 67) ? (__bf16)W1[k * 128 + n] : (__bf16)0.0f;
  }
  if (t < 128 * 128) {
    const int n = t >> 7, k = t & 127;
    w2t[t] = (__bf16)W2[k * 128 + n];
  }
  {
    const int n = t >> 7, k = t & 127;   // t < 256*128 always
    w3t[t] = (__bf16)W3[k * 256 + n];
  }
}

// ---------------------------------------------------------------------------
__device__ __forceinline__ f32x2 pk_sub(f32x2 a, f32x2 b) {
  f32x2 d;
  asm("v_pk_add_f32 %0, %1, %2 neg_lo:[0,1] neg_hi:[0,1]" : "=v"(d) : "v"(a), "v"(b));
  return d;
}
__device__ __forceinline__ f32x2 pk_mul(f32x2 a, f32x2 b) {
  f32x2 d;
  asm("v_pk_mul_f32 %0, %1, %2" : "=v"(d) : "v"(a), "v"(b));
  return d;
}
__device__ __forceinline__ f32x2 pk_add(f32x2 a, f32x2 b) {
  f32x2 d;
  asm("v_pk_add_f32 %0, %1, %2" : "=v"(d) : "v"(a), "v"(b));
  return d;
}

template <int CTRL>
__device__ __forceinline__ unsigned long long dpp_max_u64(unsigned long long k) {
  unsigned lo = (unsigned)__builtin_amdgcn_update_dpp(0, (int)(unsigned)k,         CTRL, 0xF, 0xF, true);
  unsigned hi = (unsigned)__builtin_amdgcn_update_dpp(0, (int)(unsigned)(k >> 32), CTRL, 0xF, 0xF, true);
  unsigned long long p = ((unsigned long long)hi << 32) | lo;
  return p > k ? p : k;
}

union ShU {
  struct { float4 pp[N_]; unsigned long long sw[2][4]; } f;   // fps / knn view
  struct { __bf16 A[128 * AST]; __bf16 Bv[128 * AST]; } g;    // mlp view
};

// ---------------------------------------------------------------------------
__global__ __launch_bounds__(256) void fused_kernel(
    const float* __restrict__ pos, const float* __restrict__ x,
    const float* __restrict__ b1, const float* __restrict__ b2,
    const float* __restrict__ b3,
    const __bf16* __restrict__ w1t, const __bf16* __restrict__ w2t,
    const __bf16* __restrict__ w3t,
    int* __restrict__ ipub, int* __restrict__ ctr,
    float* __restrict__ out, float* __restrict__ pos_s) {
  __shared__ alignas(16) ShU sh;
  __shared__ int sh_item;
  const int tid = threadIdx.x;

  if (blockIdx.x < B_) {
    // ================= FPS producer (R7 body, vmcnt-free barrier) =============
    __builtin_amdgcn_s_setprio(3);
    const int b = blockIdx.x;
    const float* pb = pos + (size_t)b * N_ * 3;
    for (int i = tid; i < N_; i += 256)
      sh.f.pp[i] = make_float4(pb[3 * i], pb[3 * i + 1], pb[3 * i + 2], 0.0f);
    __syncthreads();

    f32x2 X2[8], Y2[8], Z2[8];
    float D[16];
    unsigned lo16[16];
    const unsigned ntid = ~(unsigned)tid;
#pragma unroll
    for (int j = 0; j < 8; j++) {
      float4 p0 = sh.f.pp[tid + ((2 * j) << 8)];
      float4 p1 = sh.f.pp[tid + ((2 * j + 1) << 8)];
      X2[j][0] = p0.x; X2[j][1] = p1.x;
      Y2[j][0] = p0.y; Y2[j][1] = p1.y;
      Z2[j][0] = p0.z; Z2[j][1] = p1.z;
      D[2 * j] = 1e30f; D[2 * j + 1] = 1e30f;
      lo16[2 * j]     = ntid - (unsigned)((2 * j) << 8);
      lo16[2 * j + 1] = ntid - (unsigned)((2 * j + 1) << 8);
    }

    float4 q = sh.f.pp[0];
    if (tid == 0) {
      __hip_atomic_store(ipub + b * M_, 1, __ATOMIC_RELAXED,
                         __HIP_MEMORY_SCOPE_AGENT);   // idx 0, published as 0+1
      float* o = pos_s + (size_t)b * M_ * 3;
      o[0] = q.x; o[1] = q.y; o[2] = q.z;
    }

    for (int i = 1; i < M_; i++) {
      f32x2 qx; qx[0] = q.x; qx[1] = q.x;
      f32x2 qy; qy[0] = q.y; qy[1] = q.y;
      f32x2 qz; qz[0] = q.z; qz[1] = q.z;
      unsigned long long key[16];
#pragma unroll
      for (int j = 0; j < 8; j++) {
        f32x2 dx = pk_sub(X2[j], qx);
        f32x2 dy = pk_sub(Y2[j], qy);
        f32x2 dz = pk_sub(Z2[j], qz);
        f32x2 t0 = pk_mul(dx, dx);
        f32x2 t1 = pk_mul(dy, dy);
        f32x2 s  = pk_add(t0, t1);
        f32x2 t2 = pk_mul(dz, dz);
        f32x2 d2 = pk_add(s, t2);
        D[2 * j]     = fminf(D[2 * j],     d2[0]);
        D[2 * j + 1] = fminf(D[2 * j + 1], d2[1]);
        key[2 * j]     = ((unsigned long long)__float_as_uint(D[2 * j])     << 32) | lo16[2 * j];
        key[2 * j + 1] = ((unsigned long long)__float_as_uint(D[2 * j + 1]) << 32) | lo16[2 * j + 1];
      }
#pragma unroll
      for (int s = 8; s > 0; s >>= 1)
#pragma unroll
        for (int k = 0; k < s; k++)
          if (key[k + s] > key[k]) key[k] = key[k + s];
      unsigned long long kk = key[0];

      // full-wave VALU-pipe reduce: lane 63 ends with the wave max
      kk = dpp_max_u64<0xB1>(kk);    // quad_perm xor1
      kk = dpp_max_u64<0x4E>(kk);    // quad_perm xor2
      kk = dpp_max_u64<0x141>(kk);   // row_half_mirror (xor4)
      kk = dpp_max_u64<0x140>(kk);   // row_mirror (xor8)
      kk = dpp_max_u64<0x142>(kk);   // row_bcast15
      kk = dpp_max_u64<0x143>(kk);   // row_bcast31

      const int par = i & 1;
      if ((tid & 63) == 63) sh.f.sw[par][tid >> 6] = kk;
      // LDS-only fence + raw barrier: do NOT drain tid0's global stores
      // (ipub/pos_s are fire-and-forget; __syncthreads would vmcnt(0) here).
      asm volatile("s_waitcnt lgkmcnt(0)" ::: "memory");
      __builtin_amdgcn_s_barrier();

      const ulonglong2 v01 = *(const ulonglong2*)&sh.f.sw[par][0];
      const ulonglong2 v23 = *(const ulonglong2*)&sh.f.sw[par][2];
      // load all 4 candidate positions in parallel with the compare chain
      const int c0 = (int)(~(unsigned)v01.x), c1 = (int)(~(unsigned)v01.y);
      const int c2 = (int)(~(unsigned)v23.x), c3 = (int)(~(unsigned)v23.y);
      float4 q0 = sh.f.pp[c0], q1 = sh.f.pp[c1], q2 = sh.f.pp[c2], q3 = sh.f.pp[c3];
      unsigned long long k01, k23; float4 q01, q23; int i01, i23;
      if (v01.y > v01.x) { k01 = v01.y; q01 = q1; i01 = c1; }
      else               { k01 = v01.x; q01 = q0; i01 = c0; }
      if (v23.y > v23.x) { k23 = v23.y; q23 = q3; i23 = c3; }
      else               { k23 = v23.x; q23 = q2; i23 = c2; }
      int cur;
      if (k23 > k01) { q = q23; cur = i23; }
      else           { q = q01; cur = i01; }

      if (tid == 0) {
        __hip_atomic_store(ipub + b * M_ + i, cur + 1, __ATOMIC_RELAXED,
                           __HIP_MEMORY_SCOPE_AGENT);   // datum == flag
        float* o = pos_s + ((size_t)b * M_ + i) * 3;
        o[0] = q.x; o[1] = q.y; o[2] = q.z;
      }
    }
    return;
  }

  // ================= persistent worker: kNN + MLP per item =================
  const int w    = tid >> 6;
  const int lane = tid & 63;

  for (;;) {
    if (tid == 0) sh_item = atomicAdd(ctr, 1);
    __syncthreads();
    const int it = sh_item;
    if (it >= NITEM) return;
    const int b    = it & 15;
    const int mset = it >> 4;
    const int m    = mset * 4 + w;

    __syncthreads();   // previous item's LDS reads complete before restage
    {
      const float* pb = pos + (size_t)b * N_ * 3;
      for (int i = tid; i < N_; i += 256)
        sh.f.pp[i] = make_float4(pb[3 * i], pb[3 * i + 1], pb[3 * i + 2], 0.0f);
    }
    __syncthreads();   // staging visible to all waves

    // per-wave poll of its own published index (relaxed agent load; the
    // word itself is the ready-flag, so no acquire fence is needed)
    int ci0 = 0;
    if (lane == 0) {
      int v;
      while ((v = __hip_atomic_load(ipub + b * M_ + m, __ATOMIC_RELAXED,
                                    __HIP_MEMORY_SCOPE_AGENT)) == 0)
        __builtin_amdgcn_s_sleep(8);
      ci0 = v - 1;
    }
    const int ci = __shfl(ci0, 0);
    const float4 c = sh.f.pp[ci];

    // ---- kNN pass A: distances + lane-min key ----
    float d2v[64];
    unsigned long long kmin = ~0ull;
#pragma unroll
    for (int t = 0; t < 64; t++) {
      const int j = t * 64 + lane;
      const float4 p = sh.f.pp[j];
      float dx = __fsub_rn(p.x, c.x);
      float dy = __fsub_rn(p.y, c.y);
      float dz = __fsub_rn(p.z, c.z);
      float d  = __fadd_rn(__fadd_rn(__fmul_rn(dx, dx), __fmul_rn(dy, dy)),
                           __fmul_rn(dz, dz));
      d2v[t] = d;
      const unsigned long long k64 =
          ((unsigned long long)__float_as_uint(d) << 32) | (unsigned int)j;
      if (k64 < kmin) kmin = k64;
    }

    // ---- bitonic sort of lane-min keys; seed top-32; threshold T0 ----
    unsigned long long sk = kmin;
#pragma unroll
    for (int size = 2; size <= 64; size <<= 1) {
#pragma unroll
      for (int stride = size >> 1; stride > 0; stride >>= 1) {
        const unsigned long long other = __shfl_xor(sk, stride);
        const bool up      = ((lane & size) == 0);
        const bool lowhalf = ((lane & stride) == 0);
        const bool takeMin = (up == lowhalf);
        const bool swp     = takeMin ? (other < sk) : (other > sk);
        if (swp) sk = other;
      }
    }
    const unsigned long long T0 = __shfl(sk, 31);
    const bool seeded = (kmin <= T0);

    unsigned long long rkey = (lane < 32) ? sk : ~0ull;
    unsigned long long wk   = T0;

    // ---- pass B: scan, skipping seeded keys ----
#pragma unroll
    for (int t = 0; t < 64; t++) {
      const int j = t * 64 + lane;
      const unsigned long long k64 =
          ((unsigned long long)__float_as_uint(d2v[t]) << 32) | (unsigned int)j;
      const bool skip = seeded && (k64 == kmin);
      unsigned long long mask = __ballot((k64 < wk) && !skip);
      if (mask) {
        while (mask) {
          const int src = __ffsll((unsigned long long)mask) - 1;
          mask &= mask - 1;
          const unsigned long long cand = __shfl(k64, src);
          const int pos_i = (int)__popcll(__ballot(rkey < cand));  // >=32 -> no-op
          const unsigned long long sh_ = __shfl_up(rkey, 1);
          if (lane < 32) {
            if (lane == pos_i)      rkey = cand;
            else if (lane > pos_i)  rkey = sh_;
          }
        }
        wk = __shfl(rkey, 31);
      }
    }
    const int njl = (int)(rkey & 0xFFFFull);   // valid in lanes 0..31
    __syncthreads();   // all pp reads done before mlp buffers alias it

    // ---- gather: wave w fills rows [32w,32w+32) for its centroid ----
    {
      const int rl   = lane >> 1;
      const int half = lane & 1;
      const int r    = w * 32 + rl;
      const int nj   = __shfl(njl, rl);
      const float4* xr = (const float4*)(x + ((size_t)(b * N_ + nj)) * 64 + half * 32);
      __bf16* dst = &sh.g.A[r * AST + half * 32];
#pragma unroll
      for (int t = 0; t < 8; t++) {
        float4 v = xr[t];
        bf16x4 u;
        u[0] = (__bf16)v.x; u[1] = (__bf16)v.y; u[2] = (__bf16)v.z; u[3] = (__bf16)v.w;
        *(bf16x4*)(dst + t * 4) = u;
      }
      bf16x8 z;
#pragma unroll
      for (int q2 = 0; q2 < 8; q2++) z[q2] = (__bf16)0.0f;
      if (half == 0) {
        const float* pj = pos + ((size_t)(b * N_ + nj)) * 3;
        bf16x8 u = z;
        u[0] = (__bf16)(pj[0] - c.x);
        u[1] = (__bf16)(pj[1] - c.y);
        u[2] = (__bf16)(pj[2] - c.z);
        *(bf16x8*)&sh.g.A[r * AST + 64] = u;
        *(bf16x8*)&sh.g.A[r * AST + 72] = z;
      } else {
        *(bf16x8*)&sh.g.A[r * AST + 80] = z;
        *(bf16x8*)&sh.g.A[r * AST + 88] = z;
      }
    }
    __syncthreads();

    const int lrow = lane & 15;
    const int lk8  = (lane >> 4) << 3;
    const int orow = (lane >> 4) << 2;

    // ---- L1: msg(96) @ W1 -> relu -> Bv. Wave w: cols [32w,32w+32) ----
    {
      f32x4 acc[8][2];
#pragma unroll
      for (int n = 0; n < 2; n++) {
        const float bv = b1[(2 * w + n) * 16 + lrow];
        f32x4 a = {bv, bv, bv, bv};
#pragma unroll
        for (int rt = 0; rt < 8; rt++) acc[rt][n] = a;
      }
#pragma unroll
      for (int s = 0; s < 3; s++) {
        bf16x8 a[8];
#pragma unroll
        for (int rt = 0; rt < 8; rt++)
          a[rt] = *(const bf16x8*)&sh.g.A[(rt * 16 + lrow) * AST + s * 32 + lk8];
#pragma unroll
        for (int n = 0; n < 2; n++) {
          bf16x8 bb = *(const bf16x8*)&w1t[((2 * w + n) * 16 + lrow) * 96 + s * 32 + lk8];
#pragma unroll
          for (int rt = 0; rt < 8; rt++)
            acc[rt][n] = __builtin_amdgcn_mfma_f32_16x16x32_bf16(a[rt], bb, acc[rt][n], 0, 0, 0);
        }
      }
      __syncthreads();
#pragma unroll
      for (int n = 0; n < 2; n++)
#pragma unroll
        for (int rt = 0; rt < 8; rt++)
#pragma unroll
          for (int j = 0; j < 4; j++)
            sh.g.Bv[(rt * 16 + orow + j) * AST + (2 * w + n) * 16 + lrow] =
                (__bf16)fmaxf(acc[rt][n][j], 0.0f);
    }
    __syncthreads();

    // ---- L2: Bv(128) @ W2 -> relu -> A ----
    {
      f32x4 acc[8][2];
#pragma unroll
      for (int n = 0; n < 2; n++) {
        const float bv = b2[(2 * w + n) * 16 + lrow];
        f32x4 a = {bv, bv, bv, bv};
#pragma unroll
        for (int rt = 0; rt < 8; rt++) acc[rt][n] = a;
      }
#pragma unroll
      for (int s = 0; s < 4; s++) {
        bf16x8 a[8];
#pragma unroll
        for (int rt = 0; rt < 8; rt++)
          a[rt] = *(const bf16x8*)&sh.g.Bv[(rt * 16 + lrow) * AST + s * 32 + lk8];
#pragma unroll
        for (int n = 0; n < 2; n++) {
          bf16x8 bb = *(const bf16x8*)&w2t[((2 * w + n) * 16 + lrow) * 128 + s * 32 + lk8];
#pragma unroll
          for (int rt = 0; rt < 8; rt++)
            acc[rt][n] = __builtin_amdgcn_mfma_f32_16x16x32_bf16(a[rt], bb, acc[rt][n], 0, 0, 0);
        }
      }
      __syncthreads();
#pragma unroll
      for (int n = 0; n < 2; n++)
#pragma unroll
        for (int rt = 0; rt < 8; rt++)
#pragma unroll
          for (int j = 0; j < 4; j++)
            sh.g.A[(rt * 16 + orow + j) * AST + (2 * w + n) * 16 + lrow] =
                (__bf16)fmaxf(acc[rt][n][j], 0.0f);
    }
    __syncthreads();

    // ---- L3 + maxpool. Wave w: cols [64w,64w+64) in two passes ----
#pragma unroll
    for (int np = 0; np < 2; np++) {
      f32x4 acc[8][2];
#pragma unroll
      for (int n = 0; n < 2; n++) {
        const float bv = b3[(4 * w + 2 * np + n) * 16 + lrow];
        f32x4 a = {bv, bv, bv, bv};
#pragma unroll
        for (int rt = 0; rt < 8; rt++) acc[rt][n] = a;
      }
#pragma unroll
      for (int s = 0; s < 4; s++) {
        bf16x8 a[8];
#pragma unroll
        for (int rt = 0; rt < 8; rt++)
          a[rt] = *(const bf16x8*)&sh.g.A[(rt * 16 + lrow) * AST + s * 32 + lk8];
#pragma unroll
        for (int n = 0; n < 2; n++) {
          bf16x8 bb = *(const bf16x8*)&w3t[((4 * w + 2 * np + n) * 16 + lrow) * 128 + s * 32 + lk8];
#pragma unroll
          for (int rt = 0; rt < 8; rt++)
            acc[rt][n] = __builtin_amdgcn_mfma_f32_16x16x32_bf16(a[rt], bb, acc[rt][n], 0, 0, 0);
        }
      }
#pragma unroll
      for (int ccc = 0; ccc < 4; ccc++) {
#pragma unroll
        for (int n = 0; n < 2; n++) {
          f32x4 a0 = acc[2 * ccc][n], a1 = acc[2 * ccc + 1][n];
          float v = fmaxf(fmaxf(fmaxf(a0[0], a0[1]), fmaxf(a0[2], a0[3])),
                          fmaxf(fmaxf(a1[0], a1[1]), fmaxf(a1[2], a1[3])));
          v = fmaxf(v, __shfl_xor(v, 16));
          v = fmaxf(v, __shfl_xor(v, 32));
          v = fmaxf(v, 0.0f);
          if (lane < 16)
            out[((size_t)(b * M_ + mset * 4 + ccc)) * 256 + (4 * w + 2 * np + n) * 16 + lane] = v;
        }
      }
    }
    // loop to next item
  }
}

// ---------------------------------------------------------------------------
extern "C" void kernel_launch(void* const* d_in, const int* in_sizes, int n_in,
                              void* d_out, int out_size, void* d_ws, size_t ws_size,
                              hipStream_t stream) {
  const float* x   = (const float*)d_in[0];
  const float* pos = (const float*)d_in[1];
  const float* W1  = (const float*)d_in[2];
  const float* b1  = (const float*)d_in[3];
  const float* W2  = (const float*)d_in[4];
  const float* b2  = (const float*)d_in[5];
  const float* W3  = (const float*)d_in[6];
  const float* b3  = (const float*)d_in[7];

  float* out   = (float*)d_out;
  float* pos_s = out + (size_t)B_ * M_ * 256;

  char* ws = (char*)d_ws;
  int*    ipub = (int*)ws;                        // 65536 B: published idx+1
  int*    ctr  = (int*)(ws + 65536);              // 4 B
  __bf16* w1t  = (__bf16*)(ws + 65792);           // 24576 B
  __bf16* w2t  = (__bf16*)(ws + 90368);           // 32768 B
  __bf16* w3t  = (__bf16*)(ws + 123136);          // 65536 B

  hipMemsetAsync(ws, 0, 65540, stream);           // ipub + ctr
  prep_weights<<<dim3(128), dim3(256), 0, stream>>>(W1, W2, W3, w1t, w2t, w3t);
  fused_kernel<<<dim3(B_ + NWORK), dim3(256), 0, stream>>>(
      pos, x, b1, b2, b3, w1t, w2t, w3t, ipub, ctr, out, pos_s);
}

// Round 12
// 597.783 us; speedup vs baseline: 2.0992x; 1.1118x over previous
//
#include <hip/hip_runtime.h>

// SAModule (PointNet++): FPS -> kNN(32) -> [x||rel] MLP(67->128->128->256) -> max over K.
// B=16, N=4096, C=64, M=1024, K=32.
// R11 = R10 + FPS argmax keys reduced as positive f64 (v_max_f64, 1 inst)
// instead of u64 compare+2cndmask (3 inst). Valid because keys are positive
// finite bit patterns (hi=f32bits(D>=0) <= 0x7149F2CA, lo=~idx != 0), where
// IEEE f64 ordering == unsigned bit ordering. Tree 45->15 inst, DPP 30->18.
// FPS is issue-bound (R8): ~ -84 cyc on the ~1495-cyc iteration.

#define B_    16
#define N_    4096
#define M_    1024
#define AST   136
#define NWORK 240
#define NITEM (256 * 16)   // items ordered mset-major: it = mset*16 + b

typedef __bf16 bf16x8 __attribute__((ext_vector_type(8)));
typedef __bf16 bf16x4 __attribute__((ext_vector_type(4)));
typedef float  f32x4  __attribute__((ext_vector_type(4)));
typedef float  f32x2  __attribute__((ext_vector_type(2)));

// ---------------------------------------------------------------------------
// Weight prep: transpose + cast to bf16, pad W1 K-dim 67->96 with zeros.
// ---------------------------------------------------------------------------
__global__ __launch_bounds__(256) void prep_weights(
    const float* __restrict__ W1, const float* __restrict__ W2,
    const float* __restrict__ W3,
    __bf16* __restrict__ w1t, __bf16* __restrict__ w2t, __bf16* __restrict__ w3t) {
  const int t = blockIdx.x * 256 + threadIdx.x;   // 0..32767
  if (t < 128 * 96) {
    const int n = t / 96, k = t % 96;
    w1t[t] = (k < 67) ? (__bf16)W1[k * 128 + n] : (__bf16)0.0f;
  }
  if (t < 128 * 128) {
    const int n = t >> 7, k = t & 127;
    w2t[t] = (__bf16)W2[k * 128 + n];
  }
  {
    const int n = t >> 7, k = t & 127;   // t < 256*128 always
    w3t[t] = (__bf16)W3[k * 256 + n];
  }
}

// ---------------------------------------------------------------------------
__device__ __forceinline__ f32x2 pk_sub(f32x2 a, f32x2 b) {
  f32x2 d;
  asm("v_pk_add_f32 %0, %1, %2 neg_lo:[0,1] neg_hi:[0,1]" : "=v"(d) : "v"(a), "v"(b));
  return d;
}
__device__ __forceinline__ f32x2 pk_mul(f32x2 a, f32x2 b) {
  f32x2 d;
  asm("v_pk_mul_f32 %0, %1, %2" : "=v"(d) : "v"(a), "v"(b));
  return d;
}
__device__ __forceinline__ f32x2 pk_add(f32x2 a, f32x2 b) {
  f32x2 d;
  asm("v_pk_add_f32 %0, %1, %2" : "=v"(d) : "v"(a), "v"(b));
  return d;
}

// argmax key as positive f64: hi = f32 bits of D (>=0, < 0x7FF00000), lo = ~idx.
// For such patterns IEEE f64 ordering == u64 bit ordering, so v_max_f64 is a
// 1-instruction 64-bit key max (vs cmp_u64 + 2 cndmask).
__device__ __forceinline__ double mk_key(float d, unsigned lo) {
  unsigned long long k = ((unsigned long long)__float_as_uint(d) << 32) | lo;
  return __builtin_bit_cast(double, k);
}

template <int CTRL>
__device__ __forceinline__ double dpp_max_f64(double v) {
  unsigned long long k = __builtin_bit_cast(unsigned long long, v);
  unsigned lo = (unsigned)__builtin_amdgcn_update_dpp(0, (int)(unsigned)k,         CTRL, 0xF, 0xF, true);
  unsigned hi = (unsigned)__builtin_amdgcn_update_dpp(0, (int)(unsigned)(k >> 32), CTRL, 0xF, 0xF, true);
  double p = __builtin_bit_cast(double, ((unsigned long long)hi << 32) | lo);
  return fmax(v, p);   // 0-filled lanes give +0.0, which always loses (keys > 0)
}

union ShU {
  struct { float4 pp[N_]; unsigned long long sw[2][4]; } f;   // fps / knn view
  struct { __bf16 A[128 * AST]; __bf16 Bv[128 * AST]; } g;    // mlp view
};

// ---------------------------------------------------------------------------
__global__ __launch_bounds__(256) void fused_kernel(
    const float* __restrict__ pos, const float* __restrict__ x,
    const float* __restrict__ b1, const float* __restrict__ b2,
    const float* __restrict__ b3,
    const __bf16* __restrict__ w1t, const __bf16* __restrict__ w2t,
    const __bf16* __restrict__ w3t,
    int* __restrict__ ipub, int* __restrict__ ctr,
    float* __restrict__ out, float* __restrict__ pos_s) {
  __shared__ alignas(16) ShU sh;
  __shared__ int sh_item;
  const int tid = threadIdx.x;

  if (blockIdx.x < B_) {
    // ================= FPS producer (R10 body, f64-max keys) =================
    __builtin_amdgcn_s_setprio(3);
    const int b = blockIdx.x;
    const float* pb = pos + (size_t)b * N_ * 3;
    for (int i = tid; i < N_; i += 256)
      sh.f.pp[i] = make_float4(pb[3 * i], pb[3 * i + 1], pb[3 * i + 2], 0.0f);
    __syncthreads();

    f32x2 X2[8], Y2[8], Z2[8];
    float D[16];
    unsigned lo16[16];
    const unsigned ntid = ~(unsigned)tid;
#pragma unroll
    for (int j = 0; j < 8; j++) {
      float4 p0 = sh.f.pp[tid + ((2 * j) << 8)];
      float4 p1 = sh.f.pp[tid + ((2 * j + 1) << 8)];
      X2[j][0] = p0.x; X2[j][1] = p1.x;
      Y2[j][0] = p0.y; Y2[j][1] = p1.y;
      Z2[j][0] = p0.z; Z2[j][1] = p1.z;
      D[2 * j] = 1e30f; D[2 * j + 1] = 1e30f;
      lo16[2 * j]     = ntid - (unsigned)((2 * j) << 8);
      lo16[2 * j + 1] = ntid - (unsigned)((2 * j + 1) << 8);
    }

    float4 q = sh.f.pp[0];
    if (tid == 0) {
      __hip_atomic_store(ipub + b * M_, 1, __ATOMIC_RELAXED,
                         __HIP_MEMORY_SCOPE_AGENT);   // idx 0, published as 0+1
      float* o = pos_s + (size_t)b * M_ * 3;
      o[0] = q.x; o[1] = q.y; o[2] = q.z;
    }

    for (int i = 1; i < M_; i++) {
      f32x2 qx; qx[0] = q.x; qx[1] = q.x;
      f32x2 qy; qy[0] = q.y; qy[1] = q.y;
      f32x2 qz; qz[0] = q.z; qz[1] = q.z;
      double key[16];
#pragma unroll
      for (int j = 0; j < 8; j++) {
        f32x2 dx = pk_sub(X2[j], qx);
        f32x2 dy = pk_sub(Y2[j], qy);
        f32x2 dz = pk_sub(Z2[j], qz);
        f32x2 t0 = pk_mul(dx, dx);
        f32x2 t1 = pk_mul(dy, dy);
        f32x2 s  = pk_add(t0, t1);
        f32x2 t2 = pk_mul(dz, dz);
        f32x2 d2 = pk_add(s, t2);
        D[2 * j]     = fminf(D[2 * j],     d2[0]);
        D[2 * j + 1] = fminf(D[2 * j + 1], d2[1]);
        key[2 * j]     = mk_key(D[2 * j],     lo16[2 * j]);
        key[2 * j + 1] = mk_key(D[2 * j + 1], lo16[2 * j + 1]);
      }
      // per-thread tree reduce: 15 x v_max_f64 (key order == u64 order)
#pragma unroll
      for (int s = 8; s > 0; s >>= 1)
#pragma unroll
        for (int k = 0; k < s; k++)
          key[k] = fmax(key[k], key[k + s]);
      double kk = key[0];

      // full-wave VALU-pipe reduce: lane 63 ends with the wave max
      kk = dpp_max_f64<0xB1>(kk);    // quad_perm xor1
      kk = dpp_max_f64<0x4E>(kk);    // quad_perm xor2
      kk = dpp_max_f64<0x141>(kk);   // row_half_mirror (xor4)
      kk = dpp_max_f64<0x140>(kk);   // row_mirror (xor8)
      kk = dpp_max_f64<0x142>(kk);   // row_bcast15
      kk = dpp_max_f64<0x143>(kk);   // row_bcast31

      const int par = i & 1;
      if ((tid & 63) == 63)
        sh.f.sw[par][tid >> 6] = __builtin_bit_cast(unsigned long long, kk);
      // LDS-only fence + raw barrier (global stores stay fire-and-forget)
      asm volatile("s_waitcnt lgkmcnt(0)" ::: "memory");
      __builtin_amdgcn_s_barrier();

      const ulonglong2 v01 = *(const ulonglong2*)&sh.f.sw[par][0];
      const ulonglong2 v23 = *(const ulonglong2*)&sh.f.sw[par][2];
      // load all 4 candidate positions in parallel with the compare chain
      const int c0 = (int)(~(unsigned)v01.x), c1 = (int)(~(unsigned)v01.y);
      const int c2 = (int)(~(unsigned)v23.x), c3 = (int)(~(unsigned)v23.y);
      float4 q0 = sh.f.pp[c0], q1 = sh.f.pp[c1], q2 = sh.f.pp[c2], q3 = sh.f.pp[c3];
      unsigned long long k01, k23; float4 q01, q23; int i01, i23;
      if (v01.y > v01.x) { k01 = v01.y; q01 = q1; i01 = c1; }
      else               { k01 = v01.x; q01 = q0; i01 = c0; }
      if (v23.y > v23.x) { k23 = v23.y; q23 = q3; i23 = c3; }
      else               { k23 = v23.x; q23 = q2; i23 = c2; }
      int cur;
      if (k23 > k01) { q = q23; cur = i23; }
      else           { q = q01; cur = i01; }

      if (tid == 0) {
        __hip_atomic_store(ipub + b * M_ + i, cur + 1, __ATOMIC_RELAXED,
                           __HIP_MEMORY_SCOPE_AGENT);   // datum == flag
        float* o = pos_s + ((size_t)b * M_ + i) * 3;
        o[0] = q.x; o[1] = q.y; o[2] = q.z;
      }
    }
    return;
  }

  // ================= persistent worker: kNN + MLP per item =================
  const int w    = tid >> 6;
  const int lane = tid & 63;

  for (;;) {
    if (tid == 0) sh_item = atomicAdd(ctr, 1);
    __syncthreads();
    const int it = sh_item;
    if (it >= NITEM) return;
    const int b    = it & 15;
    const int mset = it >> 4;
    const int m    = mset * 4 + w;

    __syncthreads();   // previous item's LDS reads complete before restage
    {
      const float* pb = pos + (size_t)b * N_ * 3;
      for (int i = tid; i < N_; i += 256)
        sh.f.pp[i] = make_float4(pb[3 * i], pb[3 * i + 1], pb[3 * i + 2], 0.0f);
    }
    __syncthreads();   // staging visible to all waves

    // per-wave poll of its own published index (relaxed agent load; the
    // word itself is the ready-flag, so no acquire fence is needed)
    int ci0 = 0;
    if (lane == 0) {
      int v;
      while ((v = __hip_atomic_load(ipub + b * M_ + m, __ATOMIC_RELAXED,
                                    __HIP_MEMORY_SCOPE_AGENT)) == 0)
        __builtin_amdgcn_s_sleep(8);
      ci0 = v - 1;
    }
    const int ci = __shfl(ci0, 0);
    const float4 c = sh.f.pp[ci];

    // ---- kNN pass A: distances + lane-min key ----
    float d2v[64];
    unsigned long long kmin = ~0ull;
#pragma unroll
    for (int t = 0; t < 64; t++) {
      const int j = t * 64 + lane;
      const float4 p = sh.f.pp[j];
      float dx = __fsub_rn(p.x, c.x);
      float dy = __fsub_rn(p.y, c.y);
      float dz = __fsub_rn(p.z, c.z);
      float d  = __fadd_rn(__fadd_rn(__fmul_rn(dx, dx), __fmul_rn(dy, dy)),
                           __fmul_rn(dz, dz));
      d2v[t] = d;
      const unsigned long long k64 =
          ((unsigned long long)__float_as_uint(d) << 32) | (unsigned int)j;
      if (k64 < kmin) kmin = k64;
    }

    // ---- bitonic sort of lane-min keys; seed top-32; threshold T0 ----
    unsigned long long sk = kmin;
#pragma unroll
    for (int size = 2; size <= 64; size <<= 1) {
#pragma unroll
      for (int stride = size >> 1; stride > 0; stride >>= 1) {
        const unsigned long long other = __shfl_xor(sk, stride);
        const bool up      = ((lane & size) == 0);
        const bool lowhalf = ((lane & stride) == 0);
        const bool takeMin = (up == lowhalf);
        const bool swp     = takeMin ? (other < sk) : (other > sk);
        if (swp) sk = other;
      }
    }
    const unsigned long long T0 = __shfl(sk, 31);
    const bool seeded = (kmin <= T0);

    unsigned long long rkey = (lane < 32) ? sk : ~0ull;
    unsigned long long wk   = T0;

    // ---- pass B: scan, skipping seeded keys ----
#pragma unroll
    for (int t = 0; t < 64; t++) {
      const int j = t * 64 + lane;
      const unsigned long long k64 =
          ((unsigned long long)__float_as_uint(d2v[t]) << 32) | (unsigned int)j;
      const bool skip = seeded && (k64 == kmin);
      unsigned long long mask = __ballot((k64 < wk) && !skip);
      if (mask) {
        while (mask) {
          const int src = __ffsll((unsigned long long)mask) - 1;
          mask &= mask - 1;
          const unsigned long long cand = __shfl(k64, src);
          const int pos_i = (int)__popcll(__ballot(rkey < cand));  // >=32 -> no-op
          const unsigned long long sh_ = __shfl_up(rkey, 1);
          if (lane < 32) {
            if (lane == pos_i)      rkey = cand;
            else if (lane > pos_i)  rkey = sh_;
          }
        }
        wk = __shfl(rkey, 31);
      }
    }
    const int njl = (int)(rkey & 0xFFFFull);   // valid in lanes 0..31
    __syncthreads();   // all pp reads done before mlp buffers alias it

    // ---- gather: wave w fills rows [32w,32w+32) for its centroid ----
    {
      const int rl   = lane >> 1;
      const int half = lane & 1;
      const int r    = w * 32 + rl;
      const int nj   = __shfl(njl, rl);
      const float4* xr = (const float4*)(x + ((size_t)(b * N_ + nj)) * 64 + half * 32);
      __bf16* dst = &sh.g.A[r * AST + half * 32];
#pragma unroll
      for (int t = 0; t < 8; t++) {
        float4 v = xr[t];
        bf16x4 u;
        u[0] = (__bf16)v.x; u[1] = (__bf16)v.y; u[2] = (__bf16)v.z; u[3] = (__bf16)v.w;
        *(bf16x4*)(dst + t * 4) = u;
      }
      bf16x8 z;
#pragma unroll
      for (int q2 = 0; q2 < 8; q2++) z[q2] = (__bf16)0.0f;
      if (half == 0) {
        const float* pj = pos + ((size_t)(b * N_ + nj)) * 3;
        bf16x8 u = z;
        u[0] = (__bf16)(pj[0] - c.x);
        u[1] = (__bf16)(pj[1] - c.y);
        u[2] = (__bf16)(pj[2] - c.z);
        *(bf16x8*)&sh.g.A[r * AST + 64] = u;
        *(bf16x8*)&sh.g.A[r * AST + 72] = z;
      } else {
        *(bf16x8*)&sh.g.A[r * AST + 80] = z;
        *(bf16x8*)&sh.g.A[r * AST + 88] = z;
      }
    }
    __syncthreads();

    const int lrow = lane & 15;
    const int lk8  = (lane >> 4) << 3;
    const int orow = (lane >> 4) << 2;

    // ---- L1: msg(96) @ W1 -> relu -> Bv. Wave w: cols [32w,32w+32) ----
    {
      f32x4 acc[8][2];
#pragma unroll
      for (int n = 0; n < 2; n++) {
        const float bv = b1[(2 * w + n) * 16 + lrow];
        f32x4 a = {bv, bv, bv, bv};
#pragma unroll
        for (int rt = 0; rt < 8; rt++) acc[rt][n] = a;
      }
#pragma unroll
      for (int s = 0; s < 3; s++) {
        bf16x8 a[8];
#pragma unroll
        for (int rt = 0; rt < 8; rt++)
          a[rt] = *(const bf16x8*)&sh.g.A[(rt * 16 + lrow) * AST + s * 32 + lk8];
#pragma unroll
        for (int n = 0; n < 2; n++) {
          bf16x8 bb = *(const bf16x8*)&w1t[((2 * w + n) * 16 + lrow) * 96 + s * 32 + lk8];
#pragma unroll
          for (int rt = 0; rt < 8; rt++)
            acc[rt][n] = __builtin_amdgcn_mfma_f32_16x16x32_bf16(a[rt], bb, acc[rt][n], 0, 0, 0);
        }
      }
      __syncthreads();
#pragma unroll
      for (int n = 0; n < 2; n++)
#pragma unroll
        for (int rt = 0; rt < 8; rt++)
#pragma unroll
          for (int j = 0; j < 4; j++)
            sh.g.Bv[(rt * 16 + orow + j) * AST + (2 * w + n) * 16 + lrow] =
                (__bf16)fmaxf(acc[rt][n][j], 0.0f);
    }
    __syncthreads();

    // ---- L2: Bv(128) @ W2 -> relu -> A ----
    {
      f32x4 acc[8][2];
#pragma unroll
      for (int n = 0; n < 2; n++) {
        const float bv = b2[(2 * w + n) * 16 + lrow];
        f32x4 a = {bv, bv, bv, bv};
#pragma unroll
        for (int rt = 0; rt < 8; rt++) acc[rt][n] = a;
      }
#pragma unroll
      for (int s = 0; s < 4; s++) {
        bf16x8 a[8];
#pragma unroll
        for (int rt = 0; rt < 8; rt++)
          a[rt] = *(const bf16x8*)&sh.g.Bv[(rt * 16 + lrow) * AST + s * 32 + lk8];
#pragma unroll
        for (int n = 0; n < 2; n++) {
          bf16x8 bb = *(const bf16x8*)&w2t[((2 * w + n) * 16 + lrow) * 128 + s * 32 + lk8];
#pragma unroll
          for (int rt = 0; rt < 8; rt++)
            acc[rt][n] = __builtin_amdgcn_mfma_f32_16x16x32_bf16(a[rt], bb, acc[rt][n], 0, 0, 0);
        }
      }
      __syncthreads();
#pragma unroll
      for (int n = 0; n < 2; n++)
#pragma unroll
        for (int rt = 0; rt < 8; rt++)
#pragma unroll
          for (int j = 0; j < 4; j++)
            sh.g.A[(rt * 16 + orow + j) * AST + (2 * w + n) * 16 + lrow] =
                (__bf16)fmaxf(acc[rt][n][j], 0.0f);
    }
    __syncthreads();

    // ---- L3 + maxpool. Wave w: cols [64w,64w+64) in two passes ----
#pragma unroll
    for (int np = 0; np < 2; np++) {
      f32x4 acc[8][2];
#pragma unroll
      for (int n = 0; n < 2; n++) {
        const float bv = b3[(4 * w + 2 * np + n) * 16 + lrow];
        f32x4 a = {bv, bv, bv, bv};
#pragma unroll
        for (int rt = 0; rt < 8; rt++) acc[rt][n] = a;
      }
#pragma unroll
      for (int s = 0; s < 4; s++) {
        bf16x8 a[8];
#pragma unroll
        for (int rt = 0; rt < 8; rt++)
          a[rt] = *(const bf16x8*)&sh.g.A[(rt * 16 + lrow) * AST + s * 32 + lk8];
#pragma unroll
        for (int n = 0; n < 2; n++) {
          bf16x8 bb = *(const bf16x8*)&w3t[((4 * w + 2 * np + n) * 16 + lrow) * 128 + s * 32 + lk8];
#pragma unroll
          for (int rt = 0; rt < 8; rt++)
            acc[rt][n] = __builtin_amdgcn_mfma_f32_16x16x32_bf16(a[rt], bb, acc[rt][n], 0, 0, 0);
        }
      }
#pragma unroll
      for (int ccc = 0; ccc < 4; ccc++) {
#pragma unroll
        for (int n = 0; n < 2; n++) {
          f32x4 a0 = acc[2 * ccc][n], a1 = acc[2 * ccc + 1][n];
          float v = fmaxf(fmaxf(fmaxf(a0[0], a0[1]), fmaxf(a0[2], a0[3])),
                          fmaxf(fmaxf(a1[0], a1[1]), fmaxf(a1[2], a1[3])));
          v = fmaxf(v, __shfl_xor(v, 16));
          v = fmaxf(v, __shfl_xor(v, 32));
          v = fmaxf(v, 0.0f);
          if (lane < 16)
            out[((size_t)(b * M_ + mset * 4 + ccc)) * 256 + (4 * w + 2 * np + n) * 16 + lane] = v;
        }
      }
    }
    // loop to next item
  }
}

// ---------------------------------------------------------------------------
extern "C" void kernel_launch(void* const* d_in, const int* in_sizes, int n_in,
                              void* d_out, int out_size, void* d_ws, size_t ws_size,
                              hipStream_t stream) {
  const float* x   = (const float*)d_in[0];
  const float* pos = (const float*)d_in[1];
  const float* W1  = (const float*)d_in[2];
  const float* b1  = (const float*)d_in[3];
  const float* W2  = (const float*)d_in[4];
  const float* b2  = (const float*)d_in[5];
  const float* W3  = (const float*)d_in[6];
  const float* b3  = (const float*)d_in[7];

  float* out   = (float*)d_out;
  float* pos_s = out + (size_t)B_ * M_ * 256;

  char* ws = (char*)d_ws;
  int*    ipub = (int*)ws;                        // 65536 B: published idx+1
  int*    ctr  = (int*)(ws + 65536);              // 4 B
  __bf16* w1t  = (__bf16*)(ws + 65792);           // 24576 B
  __bf16* w2t  = (__bf16*)(ws + 90368);           // 32768 B
  __bf16* w3t  = (__bf16*)(ws + 123136);          // 65536 B

  hipMemsetAsync(ws, 0, 65540, stream);           // ipub + ctr
  prep_weights<<<dim3(128), dim3(256), 0, stream>>>(W1, W2, W3, w1t, w2t, w3t);
  fused_kernel<<<dim3(B_ + NWORK), dim3(256), 0, stream>>>(
      pos, x, b1, b2, b3, w1t, w2t, w3t, ipub, ctr, out, pos_s);
}

// Round 13
// 594.161 us; speedup vs baseline: 2.1120x; 1.0061x over previous
//
#include <hip/hip_runtime.h>

// SAModule (PointNet++): FPS -> kNN(32) -> [x||rel] MLP(67->128->128->256) -> max over K.
// B=16, N=4096, C=64, M=1024, K=32.
// R12 = R11 + (1) FPS post-barrier select via f64 fmax (3 inst + single pp
// read; removes the last cmp+cndmask chain, R11's proven win pattern) and
// (2) FPS blocks self-process their cloud's final item (mset 255) using the
// already-staged LDS cloud + last-4 indices kept in registers -> the ~27us
// worker-tail (poll+restage+global round trip) disappears. Workers take
// msets 0..254 only (NITEM=4080).

#define B_    16
#define N_    4096
#define M_    1024
#define AST   136
#define NWORK 240
#define NITEM (255 * 16)   // worker items, mset-major: it = mset*16 + b

typedef __bf16 bf16x8 __attribute__((ext_vector_type(8)));
typedef __bf16 bf16x4 __attribute__((ext_vector_type(4)));
typedef float  f32x4  __attribute__((ext_vector_type(4)));
typedef float  f32x2  __attribute__((ext_vector_type(2)));

// ---------------------------------------------------------------------------
// Weight prep: transpose + cast to bf16, pad W1 K-dim 67->96 with zeros.
// ---------------------------------------------------------------------------
__global__ __launch_bounds__(256) void prep_weights(
    const float* __restrict__ W1, const float* __restrict__ W2,
    const float* __restrict__ W3,
    __bf16* __restrict__ w1t, __bf16* __restrict__ w2t, __bf16* __restrict__ w3t) {
  const int t = blockIdx.x * 256 + threadIdx.x;   // 0..32767
  if (t < 128 * 96) {
    const int n = t / 96, k = t % 96;
    w1t[t] = (k < 67) ? (__bf16)W1[k * 128 + n] : (__bf16)0.0f;
  }
  if (t < 128 * 128) {
    const int n = t >> 7, k = t & 127;
    w2t[t] = (__bf16)W2[k * 128 + n];
  }
  {
    const int n = t >> 7, k = t & 127;   // t < 256*128 always
    w3t[t] = (__bf16)W3[k * 256 + n];
  }
}

// ---------------------------------------------------------------------------
__device__ __forceinline__ f32x2 pk_sub(f32x2 a, f32x2 b) {
  f32x2 d;
  asm("v_pk_add_f32 %0, %1, %2 neg_lo:[0,1] neg_hi:[0,1]" : "=v"(d) : "v"(a), "v"(b));
  return d;
}
__device__ __forceinline__ f32x2 pk_mul(f32x2 a, f32x2 b) {
  f32x2 d;
  asm("v_pk_mul_f32 %0, %1, %2" : "=v"(d) : "v"(a), "v"(b));
  return d;
}
__device__ __forceinline__ f32x2 pk_add(f32x2 a, f32x2 b) {
  f32x2 d;
  asm("v_pk_add_f32 %0, %1, %2" : "=v"(d) : "v"(a), "v"(b));
  return d;
}

// argmax key as positive f64: hi = f32 bits of D (>=0, < 0x7FF00000), lo = ~idx.
// For such patterns IEEE f64 ordering == u64 bit ordering, so v_max_f64 is a
// 1-instruction 64-bit key max.
__device__ __forceinline__ double mk_key(float d, unsigned lo) {
  unsigned long long k = ((unsigned long long)__float_as_uint(d) << 32) | lo;
  return __builtin_bit_cast(double, k);
}

template <int CTRL>
__device__ __forceinline__ double dpp_max_f64(double v) {
  unsigned long long k = __builtin_bit_cast(unsigned long long, v);
  unsigned lo = (unsigned)__builtin_amdgcn_update_dpp(0, (int)(unsigned)k,         CTRL, 0xF, 0xF, true);
  unsigned hi = (unsigned)__builtin_amdgcn_update_dpp(0, (int)(unsigned)(k >> 32), CTRL, 0xF, 0xF, true);
  double p = __builtin_bit_cast(double, ((unsigned long long)hi << 32) | lo);
  return fmax(v, p);   // 0-filled lanes give +0.0, which always loses (keys > 0)
}

union ShU {
  struct { float4 pp[N_]; unsigned long long sw[2][4]; } f;   // fps / knn view
  struct { __bf16 A[128 * AST]; __bf16 Bv[128 * AST]; } g;    // mlp view
};

// ---------------------------------------------------------------------------
// kNN + gather + MLP + maxpool for one (b, mset) item. Requires sh.f.pp to
// hold cloud b as float4 and ci = this wave's centroid point index.
// ---------------------------------------------------------------------------
__device__ __forceinline__ void process_item(
    ShU& sh, int tid, int b, int mset, int ci,
    const float* __restrict__ x, const float* __restrict__ pos,
    const float* __restrict__ b1, const float* __restrict__ b2,
    const float* __restrict__ b3,
    const __bf16* __restrict__ w1t, const __bf16* __restrict__ w2t,
    const __bf16* __restrict__ w3t, float* __restrict__ out) {
  const int w    = tid >> 6;
  const int lane = tid & 63;
  const float4 c = sh.f.pp[ci];

  // ---- kNN pass A: distances + lane-min key ----
  float d2v[64];
  unsigned long long kmin = ~0ull;
#pragma unroll
  for (int t = 0; t < 64; t++) {
    const int j = t * 64 + lane;
    const float4 p = sh.f.pp[j];
    float dx = __fsub_rn(p.x, c.x);
    float dy = __fsub_rn(p.y, c.y);
    float dz = __fsub_rn(p.z, c.z);
    float d  = __fadd_rn(__fadd_rn(__fmul_rn(dx, dx), __fmul_rn(dy, dy)),
                         __fmul_rn(dz, dz));
    d2v[t] = d;
    const unsigned long long k64 =
        ((unsigned long long)__float_as_uint(d) << 32) | (unsigned int)j;
    if (k64 < kmin) kmin = k64;
  }

  // ---- bitonic sort of lane-min keys; seed top-32; threshold T0 ----
  unsigned long long sk = kmin;
#pragma unroll
  for (int size = 2; size <= 64; size <<= 1) {
#pragma unroll
    for (int stride = size >> 1; stride > 0; stride >>= 1) {
      const unsigned long long other = __shfl_xor(sk, stride);
      const bool up      = ((lane & size) == 0);
      const bool lowhalf = ((lane & stride) == 0);
      const bool takeMin = (up == lowhalf);
      const bool swp     = takeMin ? (other < sk) : (other > sk);
      if (swp) sk = other;
    }
  }
  const unsigned long long T0 = __shfl(sk, 31);
  const bool seeded = (kmin <= T0);

  unsigned long long rkey = (lane < 32) ? sk : ~0ull;
  unsigned long long wk   = T0;

  // ---- pass B: scan, skipping seeded keys ----
#pragma unroll
  for (int t = 0; t < 64; t++) {
    const int j = t * 64 + lane;
    const unsigned long long k64 =
        ((unsigned long long)__float_as_uint(d2v[t]) << 32) | (unsigned int)j;
    const bool skip = seeded && (k64 == kmin);
    unsigned long long mask = __ballot((k64 < wk) && !skip);
    if (mask) {
      while (mask) {
        const int src = __ffsll((unsigned long long)mask) - 1;
        mask &= mask - 1;
        const unsigned long long cand = __shfl(k64, src);
        const int pos_i = (int)__popcll(__ballot(rkey < cand));  // >=32 -> no-op
        const unsigned long long sh_ = __shfl_up(rkey, 1);
        if (lane < 32) {
          if (lane == pos_i)      rkey = cand;
          else if (lane > pos_i)  rkey = sh_;
        }
      }
      wk = __shfl(rkey, 31);
    }
  }
  const int njl = (int)(rkey & 0xFFFFull);   // valid in lanes 0..31
  __syncthreads();   // all pp reads done before mlp buffers alias it

  // ---- gather: wave w fills rows [32w,32w+32) for its centroid ----
  {
    const int rl   = lane >> 1;
    const int half = lane & 1;
    const int r    = w * 32 + rl;
    const int nj   = __shfl(njl, rl);
    const float4* xr = (const float4*)(x + ((size_t)(b * N_ + nj)) * 64 + half * 32);
    __bf16* dst = &sh.g.A[r * AST + half * 32];
#pragma unroll
    for (int t = 0; t < 8; t++) {
      float4 v = xr[t];
      bf16x4 u;
      u[0] = (__bf16)v.x; u[1] = (__bf16)v.y; u[2] = (__bf16)v.z; u[3] = (__bf16)v.w;
      *(bf16x4*)(dst + t * 4) = u;
    }
    bf16x8 z;
#pragma unroll
    for (int q2 = 0; q2 < 8; q2++) z[q2] = (__bf16)0.0f;
    if (half == 0) {
      const float* pj = pos + ((size_t)(b * N_ + nj)) * 3;
      bf16x8 u = z;
      u[0] = (__bf16)(pj[0] - c.x);
      u[1] = (__bf16)(pj[1] - c.y);
      u[2] = (__bf16)(pj[2] - c.z);
      *(bf16x8*)&sh.g.A[r * AST + 64] = u;
      *(bf16x8*)&sh.g.A[r * AST + 72] = z;
    } else {
      *(bf16x8*)&sh.g.A[r * AST + 80] = z;
      *(bf16x8*)&sh.g.A[r * AST + 88] = z;
    }
  }
  __syncthreads();

  const int lrow = lane & 15;
  const int lk8  = (lane >> 4) << 3;
  const int orow = (lane >> 4) << 2;

  // ---- L1: msg(96) @ W1 -> relu -> Bv. Wave w: cols [32w,32w+32) ----
  {
    f32x4 acc[8][2];
#pragma unroll
    for (int n = 0; n < 2; n++) {
      const float bv = b1[(2 * w + n) * 16 + lrow];
      f32x4 a = {bv, bv, bv, bv};
#pragma unroll
      for (int rt = 0; rt < 8; rt++) acc[rt][n] = a;
    }
#pragma unroll
    for (int s = 0; s < 3; s++) {
      bf16x8 a[8];
#pragma unroll
      for (int rt = 0; rt < 8; rt++)
        a[rt] = *(const bf16x8*)&sh.g.A[(rt * 16 + lrow) * AST + s * 32 + lk8];
#pragma unroll
      for (int n = 0; n < 2; n++) {
        bf16x8 bb = *(const bf16x8*)&w1t[((2 * w + n) * 16 + lrow) * 96 + s * 32 + lk8];
#pragma unroll
        for (int rt = 0; rt < 8; rt++)
          acc[rt][n] = __builtin_amdgcn_mfma_f32_16x16x32_bf16(a[rt], bb, acc[rt][n], 0, 0, 0);
      }
    }
    __syncthreads();
#pragma unroll
    for (int n = 0; n < 2; n++)
#pragma unroll
      for (int rt = 0; rt < 8; rt++)
#pragma unroll
        for (int j = 0; j < 4; j++)
          sh.g.Bv[(rt * 16 + orow + j) * AST + (2 * w + n) * 16 + lrow] =
              (__bf16)fmaxf(acc[rt][n][j], 0.0f);
  }
  __syncthreads();

  // ---- L2: Bv(128) @ W2 -> relu -> A ----
  {
    f32x4 acc[8][2];
#pragma unroll
    for (int n = 0; n < 2; n++) {
      const float bv = b2[(2 * w + n) * 16 + lrow];
      f32x4 a = {bv, bv, bv, bv};
#pragma unroll
      for (int rt = 0; rt < 8; rt++) acc[rt][n] = a;
    }
#pragma unroll
    for (int s = 0; s < 4; s++) {
      bf16x8 a[8];
#pragma unroll
      for (int rt = 0; rt < 8; rt++)
        a[rt] = *(const bf16x8*)&sh.g.Bv[(rt * 16 + lrow) * AST + s * 32 + lk8];
#pragma unroll
      for (int n = 0; n < 2; n++) {
        bf16x8 bb = *(const bf16x8*)&w2t[((2 * w + n) * 16 + lrow) * 128 + s * 32 + lk8];
#pragma unroll
        for (int rt = 0; rt < 8; rt++)
          acc[rt][n] = __builtin_amdgcn_mfma_f32_16x16x32_bf16(a[rt], bb, acc[rt][n], 0, 0, 0);
      }
    }
    __syncthreads();
#pragma unroll
    for (int n = 0; n < 2; n++)
#pragma unroll
      for (int rt = 0; rt < 8; rt++)
#pragma unroll
        for (int j = 0; j < 4; j++)
          sh.g.A[(rt * 16 + orow + j) * AST + (2 * w + n) * 16 + lrow] =
              (__bf16)fmaxf(acc[rt][n][j], 0.0f);
  }
  __syncthreads();

  // ---- L3 + maxpool. Wave w: cols [64w,64w+64) in two passes ----
#pragma unroll
  for (int np = 0; np < 2; np++) {
    f32x4 acc[8][2];
#pragma unroll
    for (int n = 0; n < 2; n++) {
      const float bv = b3[(4 * w + 2 * np + n) * 16 + lrow];
      f32x4 a = {bv, bv, bv, bv};
#pragma unroll
      for (int rt = 0; rt < 8; rt++) acc[rt][n] = a;
    }
#pragma unroll
    for (int s = 0; s < 4; s++) {
      bf16x8 a[8];
#pragma unroll
      for (int rt = 0; rt < 8; rt++)
        a[rt] = *(const bf16x8*)&sh.g.A[(rt * 16 + lrow) * AST + s * 32 + lk8];
#pragma unroll
      for (int n = 0; n < 2; n++) {
        bf16x8 bb = *(const bf16x8*)&w3t[((4 * w + 2 * np + n) * 16 + lrow) * 128 + s * 32 + lk8];
#pragma unroll
        for (int rt = 0; rt < 8; rt++)
          acc[rt][n] = __builtin_amdgcn_mfma_f32_16x16x32_bf16(a[rt], bb, acc[rt][n], 0, 0, 0);
      }
    }
#pragma unroll
    for (int ccc = 0; ccc < 4; ccc++) {
#pragma unroll
      for (int n = 0; n < 2; n++) {
        f32x4 a0 = acc[2 * ccc][n], a1 = acc[2 * ccc + 1][n];
        float v = fmaxf(fmaxf(fmaxf(a0[0], a0[1]), fmaxf(a0[2], a0[3])),
                        fmaxf(fmaxf(a1[0], a1[1]), fmaxf(a1[2], a1[3])));
        v = fmaxf(v, __shfl_xor(v, 16));
        v = fmaxf(v, __shfl_xor(v, 32));
        v = fmaxf(v, 0.0f);
        if (lane < 16)
          out[((size_t)(b * M_ + mset * 4 + ccc)) * 256 + (4 * w + 2 * np + n) * 16 + lane] = v;
      }
    }
  }
}

// ---------------------------------------------------------------------------
__global__ __launch_bounds__(256) void fused_kernel(
    const float* __restrict__ pos, const float* __restrict__ x,
    const float* __restrict__ b1, const float* __restrict__ b2,
    const float* __restrict__ b3,
    const __bf16* __restrict__ w1t, const __bf16* __restrict__ w2t,
    const __bf16* __restrict__ w3t,
    int* __restrict__ ipub, int* __restrict__ ctr,
    float* __restrict__ out, float* __restrict__ pos_s) {
  __shared__ alignas(16) ShU sh;
  __shared__ int sh_item;
  const int tid = threadIdx.x;

  if (blockIdx.x < B_) {
    // ================= FPS producer (R11 body + f64 select) ==================
    __builtin_amdgcn_s_setprio(3);
    const int b = blockIdx.x;
    const float* pb = pos + (size_t)b * N_ * 3;
    for (int i = tid; i < N_; i += 256)
      sh.f.pp[i] = make_float4(pb[3 * i], pb[3 * i + 1], pb[3 * i + 2], 0.0f);
    __syncthreads();

    f32x2 X2[8], Y2[8], Z2[8];
    float D[16];
    unsigned lo16[16];
    const unsigned ntid = ~(unsigned)tid;
#pragma unroll
    for (int j = 0; j < 8; j++) {
      float4 p0 = sh.f.pp[tid + ((2 * j) << 8)];
      float4 p1 = sh.f.pp[tid + ((2 * j + 1) << 8)];
      X2[j][0] = p0.x; X2[j][1] = p1.x;
      Y2[j][0] = p0.y; Y2[j][1] = p1.y;
      Z2[j][0] = p0.z; Z2[j][1] = p1.z;
      D[2 * j] = 1e30f; D[2 * j + 1] = 1e30f;
      lo16[2 * j]     = ntid - (unsigned)((2 * j) << 8);
      lo16[2 * j + 1] = ntid - (unsigned)((2 * j + 1) << 8);
    }

    float4 q = sh.f.pp[0];
    if (tid == 0) {
      __hip_atomic_store(ipub + b * M_, 1, __ATOMIC_RELAXED,
                         __HIP_MEMORY_SCOPE_AGENT);   // idx 0, published as 0+1
      float* o = pos_s + (size_t)b * M_ * 3;
      o[0] = q.x; o[1] = q.y; o[2] = q.z;
    }

    int l0 = 0, l1 = 0, l2 = 0, l3 = 0;   // fps_idx[1020..1023]
    for (int i = 1; i < M_; i++) {
      f32x2 qx; qx[0] = q.x; qx[1] = q.x;
      f32x2 qy; qy[0] = q.y; qy[1] = q.y;
      f32x2 qz; qz[0] = q.z; qz[1] = q.z;
      double key[16];
#pragma unroll
      for (int j = 0; j < 8; j++) {
        f32x2 dx = pk_sub(X2[j], qx);
        f32x2 dy = pk_sub(Y2[j], qy);
        f32x2 dz = pk_sub(Z2[j], qz);
        f32x2 t0 = pk_mul(dx, dx);
        f32x2 t1 = pk_mul(dy, dy);
        f32x2 s  = pk_add(t0, t1);
        f32x2 t2 = pk_mul(dz, dz);
        f32x2 d2 = pk_add(s, t2);
        D[2 * j]     = fminf(D[2 * j],     d2[0]);
        D[2 * j + 1] = fminf(D[2 * j + 1], d2[1]);
        key[2 * j]     = mk_key(D[2 * j],     lo16[2 * j]);
        key[2 * j + 1] = mk_key(D[2 * j + 1], lo16[2 * j + 1]);
      }
      // per-thread tree reduce: 15 x v_max_f64 (key order == u64 order)
#pragma unroll
      for (int s = 8; s > 0; s >>= 1)
#pragma unroll
        for (int k = 0; k < s; k++)
          key[k] = fmax(key[k], key[k + s]);
      double kk = key[0];

      // full-wave VALU-pipe reduce: lane 63 ends with the wave max
      kk = dpp_max_f64<0xB1>(kk);    // quad_perm xor1
      kk = dpp_max_f64<0x4E>(kk);    // quad_perm xor2
      kk = dpp_max_f64<0x141>(kk);   // row_half_mirror (xor4)
      kk = dpp_max_f64<0x140>(kk);   // row_mirror (xor8)
      kk = dpp_max_f64<0x142>(kk);   // row_bcast15
      kk = dpp_max_f64<0x143>(kk);   // row_bcast31

      const int par = i & 1;
      if ((tid & 63) == 63)
        sh.f.sw[par][tid >> 6] = __builtin_bit_cast(unsigned long long, kk);
      // LDS-only fence + raw barrier (global stores stay fire-and-forget)
      asm volatile("s_waitcnt lgkmcnt(0)" ::: "memory");
      __builtin_amdgcn_s_barrier();

      // f64-max select: 3 fmax + single dependent pp read (no cndmask chain)
      const double2 w01 = *(const double2*)&sh.f.sw[par][0];
      const double2 w23 = *(const double2*)&sh.f.sw[par][2];
      const double kwin = fmax(fmax(w01.x, w01.y), fmax(w23.x, w23.y));
      const unsigned long long kwb = __builtin_bit_cast(unsigned long long, kwin);
      const int cur = (int)(~(unsigned)kwb);
      q = sh.f.pp[cur];

      if (i >= M_ - 4) {            // capture fps_idx[1020..1023] (block-uniform)
        if      (i == M_ - 4) l0 = cur;
        else if (i == M_ - 3) l1 = cur;
        else if (i == M_ - 2) l2 = cur;
        else                  l3 = cur;
      }
      if (tid == 0) {
        __hip_atomic_store(ipub + b * M_ + i, cur + 1, __ATOMIC_RELAXED,
                           __HIP_MEMORY_SCOPE_AGENT);   // datum == flag
        float* o = pos_s + ((size_t)b * M_ + i) * 3;
        o[0] = q.x; o[1] = q.y; o[2] = q.z;
      }
    }

    // ---- self-process the final item (mset 255): pp already staged, no poll ----
    const int w = tid >> 6;
    int ci;
    if      (w == 0) ci = l0;
    else if (w == 1) ci = l1;
    else if (w == 2) ci = l2;
    else             ci = l3;
    process_item(sh, tid, b, 255, ci, x, pos, b1, b2, b3, w1t, w2t, w3t, out);
    return;
  }

  // ================= persistent worker: kNN + MLP per item =================
  const int lane = tid & 63;
  const int w    = tid >> 6;

  for (;;) {
    if (tid == 0) sh_item = atomicAdd(ctr, 1);
    __syncthreads();
    const int it = sh_item;
    if (it >= NITEM) return;
    const int b    = it & 15;
    const int mset = it >> 4;
    const int m    = mset * 4 + w;

    __syncthreads();   // previous item's LDS reads complete before restage
    {
      const float* pb = pos + (size_t)b * N_ * 3;
      for (int i = tid; i < N_; i += 256)
        sh.f.pp[i] = make_float4(pb[3 * i], pb[3 * i + 1], pb[3 * i + 2], 0.0f);
    }
    __syncthreads();   // staging visible to all waves

    // per-wave poll of its own published index (relaxed agent load; the
    // word itself is the ready-flag, so no acquire fence is needed)
    int ci0 = 0;
    if (lane == 0) {
      int v;
      while ((v = __hip_atomic_load(ipub + b * M_ + m, __ATOMIC_RELAXED,
                                    __HIP_MEMORY_SCOPE_AGENT)) == 0)
        __builtin_amdgcn_s_sleep(8);
      ci0 = v - 1;
    }
    const int ci = __shfl(ci0, 0);

    process_item(sh, tid, b, mset, ci, x, pos, b1, b2, b3, w1t, w2t, w3t, out);
    // loop to next item
  }
}

// ---------------------------------------------------------------------------
extern "C" void kernel_launch(void* const* d_in, const int* in_sizes, int n_in,
                              void* d_out, int out_size, void* d_ws, size_t ws_size,
                              hipStream_t stream) {
  const float* x   = (const float*)d_in[0];
  const float* pos = (const float*)d_in[1];
  const float* W1  = (const float*)d_in[2];
  const float* b1  = (const float*)d_in[3];
  const float* W2  = (const float*)d_in[4];
  const float* b2  = (const float*)d_in[5];
  const float* W3  = (const float*)d_in[6];
  const float* b3  = (const float*)d_in[7];

  float* out   = (float*)d_out;
  float* pos_s = out + (size_t)B_ * M_ * 256;

  char* ws = (char*)d_ws;
  int*    ipub = (int*)ws;                        // 65536 B: published idx+1
  int*    ctr  = (int*)(ws + 65536);              // 4 B
  __bf16* w1t  = (__bf16*)(ws + 65792);           // 24576 B
  __bf16* w2t  = (__bf16*)(ws + 90368);           // 32768 B
  __bf16* w3t  = (__bf16*)(ws + 123136);          // 65536 B

  hipMemsetAsync(ws, 0, 65540, stream);           // ipub + ctr
  prep_weights<<<dim3(128), dim3(256), 0, stream>>>(W1, W2, W3, w1t, w2t, w3t);
  fused_kernel<<<dim3(B_ + NWORK), dim3(256), 0, stream>>>(
      pos, x, b1, b2, b3, w1t, w2t, w3t, ipub, ctr, out, pos_s);
}

// Round 14
// 593.680 us; speedup vs baseline: 2.1137x; 1.0008x over previous
//
#include <hip/hip_runtime.h>

// SAModule (PointNet++): FPS -> kNN(32) -> [x||rel] MLP(67->128->128->256) -> max over K.
// B=16, N=4096, C=64, M=1024, K=32.
// R13 = R12 + FPS distance/key state held as PERSISTENT f64 pairs KD[16]
// (lo32 = ~idx, constant; hi32 = f32 bits of D). The per-point update is an
// in-place v_min_f32 on the hi half (zero key-packing movs/iter; R11 showed
// pack-mov elimination is the win pattern). Tree level 1 is non-destructive
// (t[8] = fmax(KD[k], KD[k+8])) so KD persists without copies.

#define B_    16
#define N_    4096
#define M_    1024
#define AST   136
#define NWORK 240
#define NITEM (255 * 16)   // worker items, mset-major: it = mset*16 + b

typedef __bf16 bf16x8 __attribute__((ext_vector_type(8)));
typedef __bf16 bf16x4 __attribute__((ext_vector_type(4)));
typedef float  f32x4  __attribute__((ext_vector_type(4)));
typedef float  f32x2  __attribute__((ext_vector_type(2)));

// ---------------------------------------------------------------------------
// Weight prep: transpose + cast to bf16, pad W1 K-dim 67->96 with zeros.
// ---------------------------------------------------------------------------
__global__ __launch_bounds__(256) void prep_weights(
    const float* __restrict__ W1, const float* __restrict__ W2,
    const float* __restrict__ W3,
    __bf16* __restrict__ w1t, __bf16* __restrict__ w2t, __bf16* __restrict__ w3t) {
  const int t = blockIdx.x * 256 + threadIdx.x;   // 0..32767
  if (t < 128 * 96) {
    const int n = t / 96, k = t % 96;
    w1t[t] = (k < 67) ? (__bf16)W1[k * 128 + n] : (__bf16)0.0f;
  }
  if (t < 128 * 128) {
    const int n = t >> 7, k = t & 127;
    w2t[t] = (__bf16)W2[k * 128 + n];
  }
  {
    const int n = t >> 7, k = t & 127;   // t < 256*128 always
    w3t[t] = (__bf16)W3[k * 256 + n];
  }
}

// ---------------------------------------------------------------------------
__device__ __forceinline__ f32x2 pk_sub(f32x2 a, f32x2 b) {
  f32x2 d;
  asm("v_pk_add_f32 %0, %1, %2 neg_lo:[0,1] neg_hi:[0,1]" : "=v"(d) : "v"(a), "v"(b));
  return d;
}
__device__ __forceinline__ f32x2 pk_mul(f32x2 a, f32x2 b) {
  f32x2 d;
  asm("v_pk_mul_f32 %0, %1, %2" : "=v"(d) : "v"(a), "v"(b));
  return d;
}
__device__ __forceinline__ f32x2 pk_add(f32x2 a, f32x2 b) {
  f32x2 d;
  asm("v_pk_add_f32 %0, %1, %2" : "=v"(d) : "v"(a), "v"(b));
  return d;
}

// argmax key as positive f64: hi = f32 bits of D (>=0, < 0x7FF00000), lo = ~idx.
// IEEE f64 ordering == u64 bit ordering for these patterns.
__device__ __forceinline__ double mk_key(float d, unsigned lo) {
  unsigned long long k = ((unsigned long long)__float_as_uint(d) << 32) | lo;
  return __builtin_bit_cast(double, k);
}
// hi-half (the f32 distance) of a key; lo-half is a per-slot constant.
__device__ __forceinline__ float kd_hi(double k) {
  return __int_as_float((int)(__builtin_bit_cast(unsigned long long, k) >> 32));
}
__device__ __forceinline__ double kd_set_hi(double k, float h) {
  unsigned long long u = __builtin_bit_cast(unsigned long long, k);
  u = (u & 0xFFFFFFFFull) | ((unsigned long long)__float_as_uint(h) << 32);
  return __builtin_bit_cast(double, u);
}

template <int CTRL>
__device__ __forceinline__ double dpp_max_f64(double v) {
  unsigned long long k = __builtin_bit_cast(unsigned long long, v);
  unsigned lo = (unsigned)__builtin_amdgcn_update_dpp(0, (int)(unsigned)k,         CTRL, 0xF, 0xF, true);
  unsigned hi = (unsigned)__builtin_amdgcn_update_dpp(0, (int)(unsigned)(k >> 32), CTRL, 0xF, 0xF, true);
  double p = __builtin_bit_cast(double, ((unsigned long long)hi << 32) | lo);
  return fmax(v, p);   // 0-filled lanes give +0.0, which always loses (keys > 0)
}

union ShU {
  struct { float4 pp[N_]; unsigned long long sw[2][4]; } f;   // fps / knn view
  struct { __bf16 A[128 * AST]; __bf16 Bv[128 * AST]; } g;    // mlp view
};

// ---------------------------------------------------------------------------
// kNN + gather + MLP + maxpool for one (b, mset) item. Requires sh.f.pp to
// hold cloud b as float4 and ci = this wave's centroid point index.
// ---------------------------------------------------------------------------
__device__ __forceinline__ void process_item(
    ShU& sh, int tid, int b, int mset, int ci,
    const float* __restrict__ x, const float* __restrict__ pos,
    const float* __restrict__ b1, const float* __restrict__ b2,
    const float* __restrict__ b3,
    const __bf16* __restrict__ w1t, const __bf16* __restrict__ w2t,
    const __bf16* __restrict__ w3t, float* __restrict__ out) {
  const int w    = tid >> 6;
  const int lane = tid & 63;
  const float4 c = sh.f.pp[ci];

  // ---- kNN pass A: distances + lane-min key ----
  float d2v[64];
  unsigned long long kmin = ~0ull;
#pragma unroll
  for (int t = 0; t < 64; t++) {
    const int j = t * 64 + lane;
    const float4 p = sh.f.pp[j];
    float dx = __fsub_rn(p.x, c.x);
    float dy = __fsub_rn(p.y, c.y);
    float dz = __fsub_rn(p.z, c.z);
    float d  = __fadd_rn(__fadd_rn(__fmul_rn(dx, dx), __fmul_rn(dy, dy)),
                         __fmul_rn(dz, dz));
    d2v[t] = d;
    const unsigned long long k64 =
        ((unsigned long long)__float_as_uint(d) << 32) | (unsigned int)j;
    if (k64 < kmin) kmin = k64;
  }

  // ---- bitonic sort of lane-min keys; seed top-32; threshold T0 ----
  unsigned long long sk = kmin;
#pragma unroll
  for (int size = 2; size <= 64; size <<= 1) {
#pragma unroll
    for (int stride = size >> 1; stride > 0; stride >>= 1) {
      const unsigned long long other = __shfl_xor(sk, stride);
      const bool up      = ((lane & size) == 0);
      const bool lowhalf = ((lane & stride) == 0);
      const bool takeMin = (up == lowhalf);
      const bool swp     = takeMin ? (other < sk) : (other > sk);
      if (swp) sk = other;
    }
  }
  const unsigned long long T0 = __shfl(sk, 31);
  const bool seeded = (kmin <= T0);

  unsigned long long rkey = (lane < 32) ? sk : ~0ull;
  unsigned long long wk   = T0;

  // ---- pass B: scan, skipping seeded keys ----
#pragma unroll
  for (int t = 0; t < 64; t++) {
    const int j = t * 64 + lane;
    const unsigned long long k64 =
        ((unsigned long long)__float_as_uint(d2v[t]) << 32) | (unsigned int)j;
    const bool skip = seeded && (k64 == kmin);
    unsigned long long mask = __ballot((k64 < wk) && !skip);
    if (mask) {
      while (mask) {
        const int src = __ffsll((unsigned long long)mask) - 1;
        mask &= mask - 1;
        const unsigned long long cand = __shfl(k64, src);
        const int pos_i = (int)__popcll(__ballot(rkey < cand));  // >=32 -> no-op
        const unsigned long long sh_ = __shfl_up(rkey, 1);
        if (lane < 32) {
          if (lane == pos_i)      rkey = cand;
          else if (lane > pos_i)  rkey = sh_;
        }
      }
      wk = __shfl(rkey, 31);
    }
  }
  const int njl = (int)(rkey & 0xFFFFull);   // valid in lanes 0..31
  __syncthreads();   // all pp reads done before mlp buffers alias it

  // ---- gather: wave w fills rows [32w,32w+32) for its centroid ----
  {
    const int rl   = lane >> 1;
    const int half = lane & 1;
    const int r    = w * 32 + rl;
    const int nj   = __shfl(njl, rl);
    const float4* xr = (const float4*)(x + ((size_t)(b * N_ + nj)) * 64 + half * 32);
    __bf16* dst = &sh.g.A[r * AST + half * 32];
#pragma unroll
    for (int t = 0; t < 8; t++) {
      float4 v = xr[t];
      bf16x4 u;
      u[0] = (__bf16)v.x; u[1] = (__bf16)v.y; u[2] = (__bf16)v.z; u[3] = (__bf16)v.w;
      *(bf16x4*)(dst + t * 4) = u;
    }
    bf16x8 z;
#pragma unroll
    for (int q2 = 0; q2 < 8; q2++) z[q2] = (__bf16)0.0f;
    if (half == 0) {
      const float* pj = pos + ((size_t)(b * N_ + nj)) * 3;
      bf16x8 u = z;
      u[0] = (__bf16)(pj[0] - c.x);
      u[1] = (__bf16)(pj[1] - c.y);
      u[2] = (__bf16)(pj[2] - c.z);
      *(bf16x8*)&sh.g.A[r * AST + 64] = u;
      *(bf16x8*)&sh.g.A[r * AST + 72] = z;
    } else {
      *(bf16x8*)&sh.g.A[r * AST + 80] = z;
      *(bf16x8*)&sh.g.A[r * AST + 88] = z;
    }
  }
  __syncthreads();

  const int lrow = lane & 15;
  const int lk8  = (lane >> 4) << 3;
  const int orow = (lane >> 4) << 2;

  // ---- L1: msg(96) @ W1 -> relu -> Bv. Wave w: cols [32w,32w+32) ----
  {
    f32x4 acc[8][2];
#pragma unroll
    for (int n = 0; n < 2; n++) {
      const float bv = b1[(2 * w + n) * 16 + lrow];
      f32x4 a = {bv, bv, bv, bv};
#pragma unroll
      for (int rt = 0; rt < 8; rt++) acc[rt][n] = a;
    }
#pragma unroll
    for (int s = 0; s < 3; s++) {
      bf16x8 a[8];
#pragma unroll
      for (int rt = 0; rt < 8; rt++)
        a[rt] = *(const bf16x8*)&sh.g.A[(rt * 16 + lrow) * AST + s * 32 + lk8];
#pragma unroll
      for (int n = 0; n < 2; n++) {
        bf16x8 bb = *(const bf16x8*)&w1t[((2 * w + n) * 16 + lrow) * 96 + s * 32 + lk8];
#pragma unroll
        for (int rt = 0; rt < 8; rt++)
          acc[rt][n] = __builtin_amdgcn_mfma_f32_16x16x32_bf16(a[rt], bb, acc[rt][n], 0, 0, 0);
      }
    }
    __syncthreads();
#pragma unroll
    for (int n = 0; n < 2; n++)
#pragma unroll
      for (int rt = 0; rt < 8; rt++)
#pragma unroll
        for (int j = 0; j < 4; j++)
          sh.g.Bv[(rt * 16 + orow + j) * AST + (2 * w + n) * 16 + lrow] =
              (__bf16)fmaxf(acc[rt][n][j], 0.0f);
  }
  __syncthreads();

  // ---- L2: Bv(128) @ W2 -> relu -> A ----
  {
    f32x4 acc[8][2];
#pragma unroll
    for (int n = 0; n < 2; n++) {
      const float bv = b2[(2 * w + n) * 16 + lrow];
      f32x4 a = {bv, bv, bv, bv};
#pragma unroll
      for (int rt = 0; rt < 8; rt++) acc[rt][n] = a;
    }
#pragma unroll
    for (int s = 0; s < 4; s++) {
      bf16x8 a[8];
#pragma unroll
      for (int rt = 0; rt < 8; rt++)
        a[rt] = *(const bf16x8*)&sh.g.Bv[(rt * 16 + lrow) * AST + s * 32 + lk8];
#pragma unroll
      for (int n = 0; n < 2; n++) {
        bf16x8 bb = *(const bf16x8*)&w2t[((2 * w + n) * 16 + lrow) * 128 + s * 32 + lk8];
#pragma unroll
        for (int rt = 0; rt < 8; rt++)
          acc[rt][n] = __builtin_amdgcn_mfma_f32_16x16x32_bf16(a[rt], bb, acc[rt][n], 0, 0, 0);
      }
    }
    __syncthreads();
#pragma unroll
    for (int n = 0; n < 2; n++)
#pragma unroll
      for (int rt = 0; rt < 8; rt++)
#pragma unroll
        for (int j = 0; j < 4; j++)
          sh.g.A[(rt * 16 + orow + j) * AST + (2 * w + n) * 16 + lrow] =
              (__bf16)fmaxf(acc[rt][n][j], 0.0f);
  }
  __syncthreads();

  // ---- L3 + maxpool. Wave w: cols [64w,64w+64) in two passes ----
#pragma unroll
  for (int np = 0; np < 2; np++) {
    f32x4 acc[8][2];
#pragma unroll
    for (int n = 0; n < 2; n++) {
      const float bv = b3[(4 * w + 2 * np + n) * 16 + lrow];
      f32x4 a = {bv, bv, bv, bv};
#pragma unroll
      for (int rt = 0; rt < 8; rt++) acc[rt][n] = a;
    }
#pragma unroll
    for (int s = 0; s < 4; s++) {
      bf16x8 a[8];
#pragma unroll
      for (int rt = 0; rt < 8; rt++)
        a[rt] = *(const bf16x8*)&sh.g.A[(rt * 16 + lrow) * AST + s * 32 + lk8];
#pragma unroll
      for (int n = 0; n < 2; n++) {
        bf16x8 bb = *(const bf16x8*)&w3t[((4 * w + 2 * np + n) * 16 + lrow) * 128 + s * 32 + lk8];
#pragma unroll
        for (int rt = 0; rt < 8; rt++)
          acc[rt][n] = __builtin_amdgcn_mfma_f32_16x16x32_bf16(a[rt], bb, acc[rt][n], 0, 0, 0);
      }
    }
#pragma unroll
    for (int ccc = 0; ccc < 4; ccc++) {
#pragma unroll
      for (int n = 0; n < 2; n++) {
        f32x4 a0 = acc[2 * ccc][n], a1 = acc[2 * ccc + 1][n];
        float v = fmaxf(fmaxf(fmaxf(a0[0], a0[1]), fmaxf(a0[2], a0[3])),
                        fmaxf(fmaxf(a1[0], a1[1]), fmaxf(a1[2], a1[3])));
        v = fmaxf(v, __shfl_xor(v, 16));
        v = fmaxf(v, __shfl_xor(v, 32));
        v = fmaxf(v, 0.0f);
        if (lane < 16)
          out[((size_t)(b * M_ + mset * 4 + ccc)) * 256 + (4 * w + 2 * np + n) * 16 + lane] = v;
      }
    }
  }
}

// ---------------------------------------------------------------------------
__global__ __launch_bounds__(256) void fused_kernel(
    const float* __restrict__ pos, const float* __restrict__ x,
    const float* __restrict__ b1, const float* __restrict__ b2,
    const float* __restrict__ b3,
    const __bf16* __restrict__ w1t, const __bf16* __restrict__ w2t,
    const __bf16* __restrict__ w3t,
    int* __restrict__ ipub, int* __restrict__ ctr,
    float* __restrict__ out, float* __restrict__ pos_s) {
  __shared__ alignas(16) ShU sh;
  __shared__ int sh_item;
  const int tid = threadIdx.x;

  if (blockIdx.x < B_) {
    // ============ FPS producer (R12 body, persistent-pair KD state) ==========
    __builtin_amdgcn_s_setprio(3);
    const int b = blockIdx.x;
    const float* pb = pos + (size_t)b * N_ * 3;
    for (int i = tid; i < N_; i += 256)
      sh.f.pp[i] = make_float4(pb[3 * i], pb[3 * i + 1], pb[3 * i + 2], 0.0f);
    __syncthreads();

    f32x2 X2[8], Y2[8], Z2[8];
    double KD[16];   // persistent keys: lo32 = ~idx (never changes), hi32 = f32bits(D)
    const unsigned ntid = ~(unsigned)tid;
#pragma unroll
    for (int j = 0; j < 8; j++) {
      float4 p0 = sh.f.pp[tid + ((2 * j) << 8)];
      float4 p1 = sh.f.pp[tid + ((2 * j + 1) << 8)];
      X2[j][0] = p0.x; X2[j][1] = p1.x;
      Y2[j][0] = p0.y; Y2[j][1] = p1.y;
      Z2[j][0] = p0.z; Z2[j][1] = p1.z;
      KD[2 * j]     = mk_key(1e30f, ntid - (unsigned)((2 * j) << 8));
      KD[2 * j + 1] = mk_key(1e30f, ntid - (unsigned)((2 * j + 1) << 8));
    }

    float4 q = sh.f.pp[0];
    if (tid == 0) {
      __hip_atomic_store(ipub + b * M_, 1, __ATOMIC_RELAXED,
                         __HIP_MEMORY_SCOPE_AGENT);   // idx 0, published as 0+1
      float* o = pos_s + (size_t)b * M_ * 3;
      o[0] = q.x; o[1] = q.y; o[2] = q.z;
    }

    int l0 = 0, l1 = 0, l2 = 0, l3 = 0;   // fps_idx[1020..1023]
    for (int i = 1; i < M_; i++) {
      f32x2 qx; qx[0] = q.x; qx[1] = q.x;
      f32x2 qy; qy[0] = q.y; qy[1] = q.y;
      f32x2 qz; qz[0] = q.z; qz[1] = q.z;
#pragma unroll
      for (int j = 0; j < 8; j++) {
        f32x2 dx = pk_sub(X2[j], qx);
        f32x2 dy = pk_sub(Y2[j], qy);
        f32x2 dz = pk_sub(Z2[j], qz);
        f32x2 t0 = pk_mul(dx, dx);
        f32x2 t1 = pk_mul(dy, dy);
        f32x2 s  = pk_add(t0, t1);
        f32x2 t2 = pk_mul(dz, dz);
        f32x2 d2 = pk_add(s, t2);
        // in-place hi-half update: v_min_f32 on the pair's hi reg, no packing
        KD[2 * j]     = kd_set_hi(KD[2 * j],     fminf(kd_hi(KD[2 * j]),     d2[0]));
        KD[2 * j + 1] = kd_set_hi(KD[2 * j + 1], fminf(kd_hi(KD[2 * j + 1]), d2[1]));
      }
      // tree reduce, level 1 non-destructive (KD persists across iterations)
      double t[8];
#pragma unroll
      for (int k = 0; k < 8; k++) t[k] = fmax(KD[k], KD[k + 8]);
#pragma unroll
      for (int s = 4; s > 0; s >>= 1)
#pragma unroll
        for (int k = 0; k < s; k++) t[k] = fmax(t[k], t[k + s]);
      double kk = t[0];

      // full-wave VALU-pipe reduce: lane 63 ends with the wave max
      kk = dpp_max_f64<0xB1>(kk);    // quad_perm xor1
      kk = dpp_max_f64<0x4E>(kk);    // quad_perm xor2
      kk = dpp_max_f64<0x141>(kk);   // row_half_mirror (xor4)
      kk = dpp_max_f64<0x140>(kk);   // row_mirror (xor8)
      kk = dpp_max_f64<0x142>(kk);   // row_bcast15
      kk = dpp_max_f64<0x143>(kk);   // row_bcast31

      const int par = i & 1;
      if ((tid & 63) == 63)
        sh.f.sw[par][tid >> 6] = __builtin_bit_cast(unsigned long long, kk);
      // LDS-only fence + raw barrier (global stores stay fire-and-forget)
      asm volatile("s_waitcnt lgkmcnt(0)" ::: "memory");
      __builtin_amdgcn_s_barrier();

      // f64-max select: 3 fmax + single dependent pp read (no cndmask chain)
      const double2 w01 = *(const double2*)&sh.f.sw[par][0];
      const double2 w23 = *(const double2*)&sh.f.sw[par][2];
      const double kwin = fmax(fmax(w01.x, w01.y), fmax(w23.x, w23.y));
      const unsigned long long kwb = __builtin_bit_cast(unsigned long long, kwin);
      const int cur = (int)(~(unsigned)kwb);
      q = sh.f.pp[cur];

      if (i >= M_ - 4) {            // capture fps_idx[1020..1023] (block-uniform)
        if      (i == M_ - 4) l0 = cur;
        else if (i == M_ - 3) l1 = cur;
        else if (i == M_ - 2) l2 = cur;
        else                  l3 = cur;
      }
      if (tid == 0) {
        __hip_atomic_store(ipub + b * M_ + i, cur + 1, __ATOMIC_RELAXED,
                           __HIP_MEMORY_SCOPE_AGENT);   // datum == flag
        float* o = pos_s + ((size_t)b * M_ + i) * 3;
        o[0] = q.x; o[1] = q.y; o[2] = q.z;
      }
    }

    // ---- self-process the final item (mset 255): pp already staged, no poll ----
    const int w = tid >> 6;
    int ci;
    if      (w == 0) ci = l0;
    else if (w == 1) ci = l1;
    else if (w == 2) ci = l2;
    else             ci = l3;
    process_item(sh, tid, b, 255, ci, x, pos, b1, b2, b3, w1t, w2t, w3t, out);
    return;
  }

  // ================= persistent worker: kNN + MLP per item =================
  const int lane = tid & 63;
  const int w    = tid >> 6;

  for (;;) {
    if (tid == 0) sh_item = atomicAdd(ctr, 1);
    __syncthreads();
    const int it = sh_item;
    if (it >= NITEM) return;
    const int b    = it & 15;
    const int mset = it >> 4;
    const int m    = mset * 4 + w;

    __syncthreads();   // previous item's LDS reads complete before restage
    {
      const float* pb = pos + (size_t)b * N_ * 3;
      for (int i = tid; i < N_; i += 256)
        sh.f.pp[i] = make_float4(pb[3 * i], pb[3 * i + 1], pb[3 * i + 2], 0.0f);
    }
    __syncthreads();   // staging visible to all waves

    // per-wave poll of its own published index (relaxed agent load; the
    // word itself is the ready-flag, so no acquire fence is needed)
    int ci0 = 0;
    if (lane == 0) {
      int v;
      while ((v = __hip_atomic_load(ipub + b * M_ + m, __ATOMIC_RELAXED,
                                    __HIP_MEMORY_SCOPE_AGENT)) == 0)
        __builtin_amdgcn_s_sleep(8);
      ci0 = v - 1;
    }
    const int ci = __shfl(ci0, 0);

    process_item(sh, tid, b, mset, ci, x, pos, b1, b2, b3, w1t, w2t, w3t, out);
    // loop to next item
  }
}

// ---------------------------------------------------------------------------
extern "C" void kernel_launch(void* const* d_in, const int* in_sizes, int n_in,
                              void* d_out, int out_size, void* d_ws, size_t ws_size,
                              hipStream_t stream) {
  const float* x   = (const float*)d_in[0];
  const float* pos = (const float*)d_in[1];
  const float* W1  = (const float*)d_in[2];
  const float* b1  = (const float*)d_in[3];
  const float* W2  = (const float*)d_in[4];
  const float* b2  = (const float*)d_in[5];
  const float* W3  = (const float*)d_in[6];
  const float* b3  = (const float*)d_in[7];

  float* out   = (float*)d_out;
  float* pos_s = out + (size_t)B_ * M_ * 256;

  char* ws = (char*)d_ws;
  int*    ipub = (int*)ws;                        // 65536 B: published idx+1
  int*    ctr  = (int*)(ws + 65536);              // 4 B
  __bf16* w1t  = (__bf16*)(ws + 65792);           // 24576 B
  __bf16* w2t  = (__bf16*)(ws + 90368);           // 32768 B
  __bf16* w3t  = (__bf16*)(ws + 123136);          // 65536 B

  hipMemsetAsync(ws, 0, 65540, stream);           // ipub + ctr
  prep_weights<<<dim3(128), dim3(256), 0, stream>>>(W1, W2, W3, w1t, w2t, w3t);
  fused_kernel<<<dim3(B_ + NWORK), dim3(256), 0, stream>>>(
      pos, x, b1, b2, b3, w1t, w2t, w3t, ipub, ctr, out, pos_s);
}

// Round 15
// 581.324 us; speedup vs baseline: 2.1587x; 1.0213x over previous
//
#include <hip/hip_runtime.h>

// SAModule (PointNet++): FPS -> kNN(32) -> [x||rel] MLP(67->128->128->256) -> max over K.
// B=16, N=4096, C=64, M=1024, K=32.
// R14 = R13 + LDS padded to 84KB/block so TWO blocks can never share a CU
// (2x84KB > 160KB). Guarantees the 16 FPS blocks own their CUs outright --
// a co-scheduled worker block (64KB restage per item through the shared LDS
// pipe/L1) would stretch the slowest FPS block, and the slowest FPS block
// sets total time. Single-lever experiment; all code paths unchanged.

#define B_    16
#define N_    4096
#define M_    1024
#define AST   136
#define NWORK 240
#define NITEM (255 * 16)   // worker items, mset-major: it = mset*16 + b

typedef __bf16 bf16x8 __attribute__((ext_vector_type(8)));
typedef __bf16 bf16x4 __attribute__((ext_vector_type(4)));
typedef float  f32x4  __attribute__((ext_vector_type(4)));
typedef float  f32x2  __attribute__((ext_vector_type(2)));

// ---------------------------------------------------------------------------
// Weight prep: transpose + cast to bf16, pad W1 K-dim 67->96 with zeros.
// ---------------------------------------------------------------------------
__global__ __launch_bounds__(256) void prep_weights(
    const float* __restrict__ W1, const float* __restrict__ W2,
    const float* __restrict__ W3,
    __bf16* __restrict__ w1t, __bf16* __restrict__ w2t, __bf16* __restrict__ w3t) {
  const int t = blockIdx.x * 256 + threadIdx.x;   // 0..32767
  if (t < 128 * 96) {
    const int n = t / 96, k = t % 96;
    w1t[t] = (k < 67) ? (__bf16)W1[k * 128 + n] : (__bf16)0.0f;
  }
  if (t < 128 * 128) {
    const int n = t >> 7, k = t & 127;
    w2t[t] = (__bf16)W2[k * 128 + n];
  }
  {
    const int n = t >> 7, k = t & 127;   // t < 256*128 always
    w3t[t] = (__bf16)W3[k * 256 + n];
  }
}

// ---------------------------------------------------------------------------
__device__ __forceinline__ f32x2 pk_sub(f32x2 a, f32x2 b) {
  f32x2 d;
  asm("v_pk_add_f32 %0, %1, %2 neg_lo:[0,1] neg_hi:[0,1]" : "=v"(d) : "v"(a), "v"(b));
  return d;
}
__device__ __forceinline__ f32x2 pk_mul(f32x2 a, f32x2 b) {
  f32x2 d;
  asm("v_pk_mul_f32 %0, %1, %2" : "=v"(d) : "v"(a), "v"(b));
  return d;
}
__device__ __forceinline__ f32x2 pk_add(f32x2 a, f32x2 b) {
  f32x2 d;
  asm("v_pk_add_f32 %0, %1, %2" : "=v"(d) : "v"(a), "v"(b));
  return d;
}

// argmax key as positive f64: hi = f32 bits of D (>=0, < 0x7FF00000), lo = ~idx.
// IEEE f64 ordering == u64 bit ordering for these patterns.
__device__ __forceinline__ double mk_key(float d, unsigned lo) {
  unsigned long long k = ((unsigned long long)__float_as_uint(d) << 32) | lo;
  return __builtin_bit_cast(double, k);
}
// hi-half (the f32 distance) of a key; lo-half is a per-slot constant.
__device__ __forceinline__ float kd_hi(double k) {
  return __int_as_float((int)(__builtin_bit_cast(unsigned long long, k) >> 32));
}
__device__ __forceinline__ double kd_set_hi(double k, float h) {
  unsigned long long u = __builtin_bit_cast(unsigned long long, k);
  u = (u & 0xFFFFFFFFull) | ((unsigned long long)__float_as_uint(h) << 32);
  return __builtin_bit_cast(double, u);
}

template <int CTRL>
__device__ __forceinline__ double dpp_max_f64(double v) {
  unsigned long long k = __builtin_bit_cast(unsigned long long, v);
  unsigned lo = (unsigned)__builtin_amdgcn_update_dpp(0, (int)(unsigned)k,         CTRL, 0xF, 0xF, true);
  unsigned hi = (unsigned)__builtin_amdgcn_update_dpp(0, (int)(unsigned)(k >> 32), CTRL, 0xF, 0xF, true);
  double p = __builtin_bit_cast(double, ((unsigned long long)hi << 32) | lo);
  return fmax(v, p);   // 0-filled lanes give +0.0, which always loses (keys > 0)
}

union ShU {
  struct { float4 pp[N_]; unsigned long long sw[2][4]; } f;   // fps / knn view
  struct { __bf16 A[128 * AST]; __bf16 Bv[128 * AST]; } g;    // mlp view
  char force_cu_exclusive[84 * 1024];   // 2x84KB > 160KB -> 1 block/CU, HW-guaranteed
};

// ---------------------------------------------------------------------------
// kNN + gather + MLP + maxpool for one (b, mset) item. Requires sh.f.pp to
// hold cloud b as float4 and ci = this wave's centroid point index.
// ---------------------------------------------------------------------------
__device__ __forceinline__ void process_item(
    ShU& sh, int tid, int b, int mset, int ci,
    const float* __restrict__ x, const float* __restrict__ pos,
    const float* __restrict__ b1, const float* __restrict__ b2,
    const float* __restrict__ b3,
    const __bf16* __restrict__ w1t, const __bf16* __restrict__ w2t,
    const __bf16* __restrict__ w3t, float* __restrict__ out) {
  const int w    = tid >> 6;
  const int lane = tid & 63;
  const float4 c = sh.f.pp[ci];

  // ---- kNN pass A: distances + lane-min key ----
  float d2v[64];
  unsigned long long kmin = ~0ull;
#pragma unroll
  for (int t = 0; t < 64; t++) {
    const int j = t * 64 + lane;
    const float4 p = sh.f.pp[j];
    float dx = __fsub_rn(p.x, c.x);
    float dy = __fsub_rn(p.y, c.y);
    float dz = __fsub_rn(p.z, c.z);
    float d  = __fadd_rn(__fadd_rn(__fmul_rn(dx, dx), __fmul_rn(dy, dy)),
                         __fmul_rn(dz, dz));
    d2v[t] = d;
    const unsigned long long k64 =
        ((unsigned long long)__float_as_uint(d) << 32) | (unsigned int)j;
    if (k64 < kmin) kmin = k64;
  }

  // ---- bitonic sort of lane-min keys; seed top-32; threshold T0 ----
  unsigned long long sk = kmin;
#pragma unroll
  for (int size = 2; size <= 64; size <<= 1) {
#pragma unroll
    for (int stride = size >> 1; stride > 0; stride >>= 1) {
      const unsigned long long other = __shfl_xor(sk, stride);
      const bool up      = ((lane & size) == 0);
      const bool lowhalf = ((lane & stride) == 0);
      const bool takeMin = (up == lowhalf);
      const bool swp     = takeMin ? (other < sk) : (other > sk);
      if (swp) sk = other;
    }
  }
  const unsigned long long T0 = __shfl(sk, 31);
  const bool seeded = (kmin <= T0);

  unsigned long long rkey = (lane < 32) ? sk : ~0ull;
  unsigned long long wk   = T0;

  // ---- pass B: scan, skipping seeded keys ----
#pragma unroll
  for (int t = 0; t < 64; t++) {
    const int j = t * 64 + lane;
    const unsigned long long k64 =
        ((unsigned long long)__float_as_uint(d2v[t]) << 32) | (unsigned int)j;
    const bool skip = seeded && (k64 == kmin);
    unsigned long long mask = __ballot((k64 < wk) && !skip);
    if (mask) {
      while (mask) {
        const int src = __ffsll((unsigned long long)mask) - 1;
        mask &= mask - 1;
        const unsigned long long cand = __shfl(k64, src);
        const int pos_i = (int)__popcll(__ballot(rkey < cand));  // >=32 -> no-op
        const unsigned long long sh_ = __shfl_up(rkey, 1);
        if (lane < 32) {
          if (lane == pos_i)      rkey = cand;
          else if (lane > pos_i)  rkey = sh_;
        }
      }
      wk = __shfl(rkey, 31);
    }
  }
  const int njl = (int)(rkey & 0xFFFFull);   // valid in lanes 0..31
  __syncthreads();   // all pp reads done before mlp buffers alias it

  // ---- gather: wave w fills rows [32w,32w+32) for its centroid ----
  {
    const int rl   = lane >> 1;
    const int half = lane & 1;
    const int r    = w * 32 + rl;
    const int nj   = __shfl(njl, rl);
    const float4* xr = (const float4*)(x + ((size_t)(b * N_ + nj)) * 64 + half * 32);
    __bf16* dst = &sh.g.A[r * AST + half * 32];
#pragma unroll
    for (int t = 0; t < 8; t++) {
      float4 v = xr[t];
      bf16x4 u;
      u[0] = (__bf16)v.x; u[1] = (__bf16)v.y; u[2] = (__bf16)v.z; u[3] = (__bf16)v.w;
      *(bf16x4*)(dst + t * 4) = u;
    }
    bf16x8 z;
#pragma unroll
    for (int q2 = 0; q2 < 8; q2++) z[q2] = (__bf16)0.0f;
    if (half == 0) {
      const float* pj = pos + ((size_t)(b * N_ + nj)) * 3;
      bf16x8 u = z;
      u[0] = (__bf16)(pj[0] - c.x);
      u[1] = (__bf16)(pj[1] - c.y);
      u[2] = (__bf16)(pj[2] - c.z);
      *(bf16x8*)&sh.g.A[r * AST + 64] = u;
      *(bf16x8*)&sh.g.A[r * AST + 72] = z;
    } else {
      *(bf16x8*)&sh.g.A[r * AST + 80] = z;
      *(bf16x8*)&sh.g.A[r * AST + 88] = z;
    }
  }
  __syncthreads();

  const int lrow = lane & 15;
  const int lk8  = (lane >> 4) << 3;
  const int orow = (lane >> 4) << 2;

  // ---- L1: msg(96) @ W1 -> relu -> Bv. Wave w: cols [32w,32w+32) ----
  {
    f32x4 acc[8][2];
#pragma unroll
    for (int n = 0; n < 2; n++) {
      const float bv = b1[(2 * w + n) * 16 + lrow];
      f32x4 a = {bv, bv, bv, bv};
#pragma unroll
      for (int rt = 0; rt < 8; rt++) acc[rt][n] = a;
    }
#pragma unroll
    for (int s = 0; s < 3; s++) {
      bf16x8 a[8];
#pragma unroll
      for (int rt = 0; rt < 8; rt++)
        a[rt] = *(const bf16x8*)&sh.g.A[(rt * 16 + lrow) * AST + s * 32 + lk8];
#pragma unroll
      for (int n = 0; n < 2; n++) {
        bf16x8 bb = *(const bf16x8*)&w1t[((2 * w + n) * 16 + lrow) * 96 + s * 32 + lk8];
#pragma unroll
        for (int rt = 0; rt < 8; rt++)
          acc[rt][n] = __builtin_amdgcn_mfma_f32_16x16x32_bf16(a[rt], bb, acc[rt][n], 0, 0, 0);
      }
    }
    __syncthreads();
#pragma unroll
    for (int n = 0; n < 2; n++)
#pragma unroll
      for (int rt = 0; rt < 8; rt++)
#pragma unroll
        for (int j = 0; j < 4; j++)
          sh.g.Bv[(rt * 16 + orow + j) * AST + (2 * w + n) * 16 + lrow] =
              (__bf16)fmaxf(acc[rt][n][j], 0.0f);
  }
  __syncthreads();

  // ---- L2: Bv(128) @ W2 -> relu -> A ----
  {
    f32x4 acc[8][2];
#pragma unroll
    for (int n = 0; n < 2; n++) {
      const float bv = b2[(2 * w + n) * 16 + lrow];
      f32x4 a = {bv, bv, bv, bv};
#pragma unroll
      for (int rt = 0; rt < 8; rt++) acc[rt][n] = a;
    }
#pragma unroll
    for (int s = 0; s < 4; s++) {
      bf16x8 a[8];
#pragma unroll
      for (int rt = 0; rt < 8; rt++)
        a[rt] = *(const bf16x8*)&sh.g.Bv[(rt * 16 + lrow) * AST + s * 32 + lk8];
#pragma unroll
      for (int n = 0; n < 2; n++) {
        bf16x8 bb = *(const bf16x8*)&w2t[((2 * w + n) * 16 + lrow) * 128 + s * 32 + lk8];
#pragma unroll
        for (int rt = 0; rt < 8; rt++)
          acc[rt][n] = __builtin_amdgcn_mfma_f32_16x16x32_bf16(a[rt], bb, acc[rt][n], 0, 0, 0);
      }
    }
    __syncthreads();
#pragma unroll
    for (int n = 0; n < 2; n++)
#pragma unroll
      for (int rt = 0; rt < 8; rt++)
#pragma unroll
        for (int j = 0; j < 4; j++)
          sh.g.A[(rt * 16 + orow + j) * AST + (2 * w + n) * 16 + lrow] =
              (__bf16)fmaxf(acc[rt][n][j], 0.0f);
  }
  __syncthreads();

  // ---- L3 + maxpool. Wave w: cols [64w,64w+64) in two passes ----
#pragma unroll
  for (int np = 0; np < 2; np++) {
    f32x4 acc[8][2];
#pragma unroll
    for (int n = 0; n < 2; n++) {
      const float bv = b3[(4 * w + 2 * np + n) * 16 + lrow];
      f32x4 a = {bv, bv, bv, bv};
#pragma unroll
      for (int rt = 0; rt < 8; rt++) acc[rt][n] = a;
    }
#pragma unroll
    for (int s = 0; s < 4; s++) {
      bf16x8 a[8];
#pragma unroll
      for (int rt = 0; rt < 8; rt++)
        a[rt] = *(const bf16x8*)&sh.g.A[(rt * 16 + lrow) * AST + s * 32 + lk8];
#pragma unroll
      for (int n = 0; n < 2; n++) {
        bf16x8 bb = *(const bf16x8*)&w3t[((4 * w + 2 * np + n) * 16 + lrow) * 128 + s * 32 + lk8];
#pragma unroll
        for (int rt = 0; rt < 8; rt++)
          acc[rt][n] = __builtin_amdgcn_mfma_f32_16x16x32_bf16(a[rt], bb, acc[rt][n], 0, 0, 0);
      }
    }
#pragma unroll
    for (int ccc = 0; ccc < 4; ccc++) {
#pragma unroll
      for (int n = 0; n < 2; n++) {
        f32x4 a0 = acc[2 * ccc][n], a1 = acc[2 * ccc + 1][n];
        float v = fmaxf(fmaxf(fmaxf(a0[0], a0[1]), fmaxf(a0[2], a0[3])),
                        fmaxf(fmaxf(a1[0], a1[1]), fmaxf(a1[2], a1[3])));
        v = fmaxf(v, __shfl_xor(v, 16));
        v = fmaxf(v, __shfl_xor(v, 32));
        v = fmaxf(v, 0.0f);
        if (lane < 16)
          out[((size_t)(b * M_ + mset * 4 + ccc)) * 256 + (4 * w + 2 * np + n) * 16 + lane] = v;
      }
    }
  }
}

// ---------------------------------------------------------------------------
__global__ __launch_bounds__(256) void fused_kernel(
    const float* __restrict__ pos, const float* __restrict__ x,
    const float* __restrict__ b1, const float* __restrict__ b2,
    const float* __restrict__ b3,
    const __bf16* __restrict__ w1t, const __bf16* __restrict__ w2t,
    const __bf16* __restrict__ w3t,
    int* __restrict__ ipub, int* __restrict__ ctr,
    float* __restrict__ out, float* __restrict__ pos_s) {
  __shared__ alignas(16) ShU sh;
  __shared__ int sh_item;
  const int tid = threadIdx.x;

  if (blockIdx.x < B_) {
    // ============ FPS producer (R13 body, CU-exclusive by LDS size) ==========
    __builtin_amdgcn_s_setprio(3);
    const int b = blockIdx.x;
    const float* pb = pos + (size_t)b * N_ * 3;
    for (int i = tid; i < N_; i += 256)
      sh.f.pp[i] = make_float4(pb[3 * i], pb[3 * i + 1], pb[3 * i + 2], 0.0f);
    __syncthreads();

    f32x2 X2[8], Y2[8], Z2[8];
    double KD[16];   // persistent keys: lo32 = ~idx (never changes), hi32 = f32bits(D)
    const unsigned ntid = ~(unsigned)tid;
#pragma unroll
    for (int j = 0; j < 8; j++) {
      float4 p0 = sh.f.pp[tid + ((2 * j) << 8)];
      float4 p1 = sh.f.pp[tid + ((2 * j + 1) << 8)];
      X2[j][0] = p0.x; X2[j][1] = p1.x;
      Y2[j][0] = p0.y; Y2[j][1] = p1.y;
      Z2[j][0] = p0.z; Z2[j][1] = p1.z;
      KD[2 * j]     = mk_key(1e30f, ntid - (unsigned)((2 * j) << 8));
      KD[2 * j + 1] = mk_key(1e30f, ntid - (unsigned)((2 * j + 1) << 8));
    }

    float4 q = sh.f.pp[0];
    if (tid == 0) {
      __hip_atomic_store(ipub + b * M_, 1, __ATOMIC_RELAXED,
                         __HIP_MEMORY_SCOPE_AGENT);   // idx 0, published as 0+1
      float* o = pos_s + (size_t)b * M_ * 3;
      o[0] = q.x; o[1] = q.y; o[2] = q.z;
    }

    int l0 = 0, l1 = 0, l2 = 0, l3 = 0;   // fps_idx[1020..1023]
    for (int i = 1; i < M_; i++) {
      f32x2 qx; qx[0] = q.x; qx[1] = q.x;
      f32x2 qy; qy[0] = q.y; qy[1] = q.y;
      f32x2 qz; qz[0] = q.z; qz[1] = q.z;
#pragma unroll
      for (int j = 0; j < 8; j++) {
        f32x2 dx = pk_sub(X2[j], qx);
        f32x2 dy = pk_sub(Y2[j], qy);
        f32x2 dz = pk_sub(Z2[j], qz);
        f32x2 t0 = pk_mul(dx, dx);
        f32x2 t1 = pk_mul(dy, dy);
        f32x2 s  = pk_add(t0, t1);
        f32x2 t2 = pk_mul(dz, dz);
        f32x2 d2 = pk_add(s, t2);
        // in-place hi-half update: v_min_f32 on the pair's hi reg, no packing
        KD[2 * j]     = kd_set_hi(KD[2 * j],     fminf(kd_hi(KD[2 * j]),     d2[0]));
        KD[2 * j + 1] = kd_set_hi(KD[2 * j + 1], fminf(kd_hi(KD[2 * j + 1]), d2[1]));
      }
      // tree reduce, level 1 non-destructive (KD persists across iterations)
      double t[8];
#pragma unroll
      for (int k = 0; k < 8; k++) t[k] = fmax(KD[k], KD[k + 8]);
#pragma unroll
      for (int s = 4; s > 0; s >>= 1)
#pragma unroll
        for (int k = 0; k < s; k++) t[k] = fmax(t[k], t[k + s]);
      double kk = t[0];

      // full-wave VALU-pipe reduce: lane 63 ends with the wave max
      kk = dpp_max_f64<0xB1>(kk);    // quad_perm xor1
      kk = dpp_max_f64<0x4E>(kk);    // quad_perm xor2
      kk = dpp_max_f64<0x141>(kk);   // row_half_mirror (xor4)
      kk = dpp_max_f64<0x140>(kk);   // row_mirror (xor8)
      kk = dpp_max_f64<0x142>(kk);   // row_bcast15
      kk = dpp_max_f64<0x143>(kk);   // row_bcast31

      const int par = i & 1;
      if ((tid & 63) == 63)
        sh.f.sw[par][tid >> 6] = __builtin_bit_cast(unsigned long long, kk);
      // LDS-only fence + raw barrier (global stores stay fire-and-forget)
      asm volatile("s_waitcnt lgkmcnt(0)" ::: "memory");
      __builtin_amdgcn_s_barrier();

      // f64-max select: 3 fmax + single dependent pp read (no cndmask chain)
      const double2 w01 = *(const double2*)&sh.f.sw[par][0];
      const double2 w23 = *(const double2*)&sh.f.sw[par][2];
      const double kwin = fmax(fmax(w01.x, w01.y), fmax(w23.x, w23.y));
      const unsigned long long kwb = __builtin_bit_cast(unsigned long long, kwin);
      const int cur = (int)(~(unsigned)kwb);
      q = sh.f.pp[cur];

      if (i >= M_ - 4) {            // capture fps_idx[1020..1023] (block-uniform)
        if      (i == M_ - 4) l0 = cur;
        else if (i == M_ - 3) l1 = cur;
        else if (i == M_ - 2) l2 = cur;
        else                  l3 = cur;
      }
      if (tid == 0) {
        __hip_atomic_store(ipub + b * M_ + i, cur + 1, __ATOMIC_RELAXED,
                           __HIP_MEMORY_SCOPE_AGENT);   // datum == flag
        float* o = pos_s + ((size_t)b * M_ + i) * 3;
        o[0] = q.x; o[1] = q.y; o[2] = q.z;
      }
    }

    // ---- self-process the final item (mset 255): pp already staged, no poll ----
    const int w = tid >> 6;
    int ci;
    if      (w == 0) ci = l0;
    else if (w == 1) ci = l1;
    else if (w == 2) ci = l2;
    else             ci = l3;
    process_item(sh, tid, b, 255, ci, x, pos, b1, b2, b3, w1t, w2t, w3t, out);
    return;
  }

  // ================= persistent worker: kNN + MLP per item =================
  const int lane = tid & 63;
  const int w    = tid >> 6;

  for (;;) {
    if (tid == 0) sh_item = atomicAdd(ctr, 1);
    __syncthreads();
    const int it = sh_item;
    if (it >= NITEM) return;
    const int b    = it & 15;
    const int mset = it >> 4;
    const int m    = mset * 4 + w;

    __syncthreads();   // previous item's LDS reads complete before restage
    {
      const float* pb = pos + (size_t)b * N_ * 3;
      for (int i = tid; i < N_; i += 256)
        sh.f.pp[i] = make_float4(pb[3 * i], pb[3 * i + 1], pb[3 * i + 2], 0.0f);
    }
    __syncthreads();   // staging visible to all waves

    // per-wave poll of its own published index (relaxed agent load; the
    // word itself is the ready-flag, so no acquire fence is needed)
    int ci0 = 0;
    if (lane == 0) {
      int v;
      while ((v = __hip_atomic_load(ipub + b * M_ + m, __ATOMIC_RELAXED,
                                    __HIP_MEMORY_SCOPE_AGENT)) == 0)
        __builtin_amdgcn_s_sleep(8);
      ci0 = v - 1;
    }
    const int ci = __shfl(ci0, 0);

    process_item(sh, tid, b, mset, ci, x, pos, b1, b2, b3, w1t, w2t, w3t, out);
    // loop to next item
  }
}

// ---------------------------------------------------------------------------
extern "C" void kernel_launch(void* const* d_in, const int* in_sizes, int n_in,
                              void* d_out, int out_size, void* d_ws, size_t ws_size,
                              hipStream_t stream) {
  const float* x   = (const float*)d_in[0];
  const float* pos = (const float*)d_in[1];
  const float* W1  = (const float*)d_in[2];
  const float* b1  = (const float*)d_in[3];
  const float* W2  = (const float*)d_in[4];
  const float* b2  = (const float*)d_in[5];
  const float* W3  = (const float*)d_in[6];
  const float* b3  = (const float*)d_in[7];

  float* out   = (float*)d_out;
  float* pos_s = out + (size_t)B_ * M_ * 256;

  char* ws = (char*)d_ws;
  int*    ipub = (int*)ws;                        // 65536 B: published idx+1
  int*    ctr  = (int*)(ws + 65536);              // 4 B
  __bf16* w1t  = (__bf16*)(ws + 65792);           // 24576 B
  __bf16* w2t  = (__bf16*)(ws + 90368);           // 32768 B
  __bf16* w3t  = (__bf16*)(ws + 123136);          // 65536 B

  hipMemsetAsync(ws, 0, 65540, stream);           // ipub + ctr
  prep_weights<<<dim3(128), dim3(256), 0, stream>>>(W1, W2, W3, w1t, w2t, w3t);
  fused_kernel<<<dim3(B_ + NWORK), dim3(256), 0, stream>>>(
      pos, x, b1, b2, b3, w1t, w2t, w3t, ipub, ctr, out, pos_s);
}